// Round 4
// baseline (6689.888 us; speedup 1.0000x reference)
//
#include <hip/hip_runtime.h>
#include <hip/hip_bf16.h>

#define NTOK 15
#define DP   128
#define DM   768
#define NH   4
#define HD   192
#define NP   64
#define EPSF 1e-5f

// ---------------------------------------------------------------------------
// Kernel 1: K^T and V from protos.  kt[j][p] (j=h*HD+d outer, p inner) so the
// attention score loop reads kt coalesced with lane==p.  V kept (p, j) so the
// rep accumulation reads coalesced over j.
// ---------------------------------------------------------------------------
__global__ __launch_bounds__(256) void kv_kernel(
    const float* __restrict__ protos,
    const float* __restrict__ wk, const float* __restrict__ bk,
    const float* __restrict__ wv, const float* __restrict__ bv,
    float* __restrict__ kt, float* __restrict__ vbuf)
{
    int r = blockIdx.x;            // proto row 0..63
    int tid = threadIdx.x;
    __shared__ float prow[DM];
    for (int i = tid; i < DM; i += 256) prow[i] = protos[r * DM + i];
    __syncthreads();
    for (int j = tid; j < DM; j += 256) {
        float aK = bk[j], aV = bv[j];
        for (int d = 0; d < DM; ++d) {
            float p = prow[d];
            aK += p * wk[d * DM + j];
            aV += p * wv[d * DM + j];
        }
        kt[j * NP + r]   = aK;     // transposed
        vbuf[r * DM + j] = aV;     // row-major
    }
}

// ---------------------------------------------------------------------------
// Kernel 2: fully fused per-row pipeline.  One block per n (B*T rows).
// LDS: pe 7.5KB + qr 45KB + small = ~54KB -> 2 blocks/CU.
// ---------------------------------------------------------------------------
__global__ __launch_bounds__(256) void row_kernel(
    const float* __restrict__ state,
    const float* __restrict__ w_scalar, const float* __restrict__ b_scalar,
    const float* __restrict__ w_patch,  const float* __restrict__ b_patch,
    const float* __restrict__ feat_emb,
    const float* __restrict__ pn_g, const float* __restrict__ pn_b,
    const float* __restrict__ wq, const float* __restrict__ bq,
    const float* __restrict__ wp, const float* __restrict__ bp,
    const float* __restrict__ wo, const float* __restrict__ bo,
    const float* __restrict__ on_g, const float* __restrict__ on_b,
    const float* __restrict__ kt, const float* __restrict__ vbuf,
    float* __restrict__ out)
{
    int n   = blockIdx.x;
    int tid = threadIdx.x;
    int wid = tid >> 6, lane = tid & 63;

    __shared__ float pe[NTOK][DP];     // patch embedding (post-LN), reused for wp
    __shared__ float qr[NTOK][DM];     // q, then overwritten in-place by rep
    __shared__ float srow[36];
    __shared__ float red[16];

    // ---- load state row --------------------------------------------------
    if (tid < 36) srow[tid] = state[n * 36 + tid];
    __syncthreads();

    // ---- build pe (15 tokens x 128) --------------------------------------
    for (int idx = tid; idx < NTOK * DP; idx += 256) {
        int t = idx / DP, d = idx % DP;
        float val;
        if (t == 0) {
            val = srow[5]  * w_scalar[0 * DP + d] + b_scalar[0 * DP + d] + feat_emb[0 * DP + d];
        } else if (t == 1) {
            val = srow[11] * w_scalar[1 * DP + d] + b_scalar[1 * DP + d] + feat_emb[1 * DP + d];
        } else if (t == 14) {
            val = srow[35] * w_scalar[2 * DP + d] + b_scalar[2 * DP + d] + feat_emb[5 * DP + d];
        } else {
            int f = (t - 2) / 4;             // 0,1,2 -> state rows 2,3,4
            int k = (t - 2) % 4;             // window start
            const float* pr = &srow[(2 + f) * 6];
            float acc = b_patch[f * DP + d] + feat_emb[(2 + f) * DP + d];
            for (int p = 0; p < 3; ++p) acc += pr[k + p] * w_patch[(f * 3 + p) * DP + d];
            val = acc;
        }
        pe[t][d] = val;
    }
    __syncthreads();

    // ---- LayerNorm(pe) over 128: 16 threads per token --------------------
    {
        int tk = tid >> 4, ln = tid & 15;
        if (tk < NTOK) {
            float s = 0.f, s2 = 0.f;
            for (int d = ln; d < DP; d += 16) { float x = pe[tk][d]; s += x; s2 += x * x; }
            for (int off = 8; off; off >>= 1) {
                s  += __shfl_xor(s,  off, 64);
                s2 += __shfl_xor(s2, off, 64);
            }
            float m   = s / DP;
            float var = s2 / DP - m * m;
            float rin = 1.0f / sqrtf(var + EPSF);
            for (int d = ln; d < DP; d += 16)
                pe[tk][d] = (pe[tk][d] - m) * rin * pn_g[d] + pn_b[d];
        }
    }
    __syncthreads();

    // ---- q = pe @ wq + bq  (15 x 768 into LDS) ---------------------------
    for (int idx = tid; idx < NTOK * DM; idx += 256) {
        int t = idx / DM, j = idx % DM;
        float acc = bq[j];
        const float* per = pe[t];
        for (int d = 0; d < DP; d += 4) {
            acc += per[d]     * wq[(d)     * DM + j];
            acc += per[d + 1] * wq[(d + 1) * DM + j];
            acc += per[d + 2] * wq[(d + 2) * DM + j];
            acc += per[d + 3] * wq[(d + 3) * DM + j];
        }
        qr[t][j] = acc;
    }
    __syncthreads();

    // ---- attention: 60 (h,t) pairs, each owned by one wave ---------------
    // score p=lane; softmax via wave shuffles; attn in registers; rep
    // overwrites q's region in-place (disjoint per pair -> no barriers).
    {
        const float scale = 0.07216878364870323f;   // 1/sqrt(192)
        for (int k = 0; k < 15; ++k) {
            int pair = k * 4 + wid;                 // 0..59
            int h = pair / NTOK, t = pair % NTOK;
            const float* qv = &qr[t][h * HD];
            float s = 0.f;
            for (int d = 0; d < HD; ++d)
                s += qv[d] * kt[(h * HD + d) * NP + lane];
            s *= scale;
            float mx = s;
            for (int off = 32; off; off >>= 1) mx = fmaxf(mx, __shfl_xor(mx, off, 64));
            float e = __expf(s - mx);
            float sum = e;
            for (int off = 32; off; off >>= 1) sum += __shfl_xor(sum, off, 64);
            float a = e / sum;
            float r0 = 0.f, r1 = 0.f, r2 = 0.f;
            for (int p = 0; p < NP; ++p) {
                float ap = __shfl(a, p, 64);
                const float* vrow = &vbuf[p * DM + h * HD];
                r0 += ap * vrow[lane];
                r1 += ap * vrow[lane + 64];
                r2 += ap * vrow[lane + 128];
            }
            qr[t][h * HD + lane]       = r0;
            qr[t][h * HD + lane + 64]  = r1;
            qr[t][h * HD + lane + 128] = r2;
        }
    }
    __syncthreads();

    // ---- out = LN(rep @ wo + bo + pe @ wp + bp), one token at a time -----
    for (int t = 0; t < NTOK; ++t) {
        int j0 = tid, j1 = tid + 256, j2 = tid + 512;
        float a0 = bo[j0] + bp[j0];
        float a1 = bo[j1] + bp[j1];
        float a2 = bo[j2] + bp[j2];
        const float* rv = qr[t];
        for (int dd = 0; dd < DM; ++dd) {
            float r = rv[dd];
            const float* wrow = &wo[dd * DM];
            a0 += r * wrow[j0]; a1 += r * wrow[j1]; a2 += r * wrow[j2];
        }
        const float* pv = pe[t];
        for (int d = 0; d < DP; ++d) {
            float p = pv[d];
            const float* wrow = &wp[d * DM];
            a0 += p * wrow[j0]; a1 += p * wrow[j1]; a2 += p * wrow[j2];
        }
        // block-wide LN reduction over 768
        float s  = a0 + a1 + a2;
        float s2 = a0 * a0 + a1 * a1 + a2 * a2;
        for (int off = 32; off; off >>= 1) {
            s  += __shfl_xor(s,  off, 64);
            s2 += __shfl_xor(s2, off, 64);
        }
        if (lane == 0) { red[wid] = s; red[8 + wid] = s2; }
        __syncthreads();
        float ts  = red[0] + red[1] + red[2] + red[3];
        float ts2 = red[8] + red[9] + red[10] + red[11];
        float m   = ts / DM;
        float var = ts2 / DM - m * m;
        float rin = 1.0f / sqrtf(var + EPSF);
        float* orow = &out[((size_t)n * NTOK + t) * DM];
        orow[j0] = (a0 - m) * rin * on_g[j0] + on_b[j0];
        orow[j1] = (a1 - m) * rin * on_g[j1] + on_b[j1];
        orow[j2] = (a2 - m) * rin * on_g[j2] + on_b[j2];
        __syncthreads();   // protect red before next token
    }
}

extern "C" void kernel_launch(void* const* d_in, const int* in_sizes, int n_in,
                              void* d_out, int out_size, void* d_ws, size_t ws_size,
                              hipStream_t stream) {
    const float* state    = (const float*)d_in[0];
    const float* w_scalar = (const float*)d_in[1];
    const float* b_scalar = (const float*)d_in[2];
    const float* w_patch  = (const float*)d_in[3];
    const float* b_patch  = (const float*)d_in[4];
    const float* feat_emb = (const float*)d_in[5];
    const float* pn_g     = (const float*)d_in[6];
    const float* pn_b     = (const float*)d_in[7];
    const float* wq       = (const float*)d_in[8];
    const float* bq       = (const float*)d_in[9];
    const float* wk       = (const float*)d_in[10];
    const float* bk       = (const float*)d_in[11];
    const float* wv       = (const float*)d_in[12];
    const float* bv       = (const float*)d_in[13];
    const float* wp       = (const float*)d_in[14];
    const float* bp       = (const float*)d_in[15];
    const float* wo       = (const float*)d_in[16];
    const float* bo       = (const float*)d_in[17];
    const float* on_g     = (const float*)d_in[18];
    const float* on_b     = (const float*)d_in[19];
    const float* protos   = (const float*)d_in[20];
    float* out  = (float*)d_out;
    float* kt   = (float*)d_ws;           // 768*64 floats
    float* vbuf = kt + DM * NP;           // 64*768 floats

    int N = in_sizes[0] / 36;             // B*T rows

    hipLaunchKernelGGL(kv_kernel, dim3(NP), dim3(256), 0, stream,
                       protos, wk, bk, wv, bv, kt, vbuf);
    hipLaunchKernelGGL(row_kernel, dim3(N), dim3(256), 0, stream,
                       state, w_scalar, b_scalar, w_patch, b_patch, feat_emb,
                       pn_g, pn_b, wq, bq, wp, bp, wo, bo, on_g, on_b,
                       kt, vbuf, out);
}

// Round 5
// 2061.975 us; speedup vs baseline: 3.2444x; 3.2444x over previous
//
#include <hip/hip_runtime.h>
#include <hip/hip_bf16.h>

#define NTOK 15
#define DP   128
#define DM   768
#define NH   4
#define HD   192
#define NP   64
#define EPSF 1e-5f

// ---------------------------------------------------------------------------
// Kernel 1: K^T and V from protos (unchanged, verified).
// ---------------------------------------------------------------------------
__global__ __launch_bounds__(256) void kv_kernel(
    const float* __restrict__ protos,
    const float* __restrict__ wk, const float* __restrict__ bk,
    const float* __restrict__ wv, const float* __restrict__ bv,
    float* __restrict__ kt, float* __restrict__ vbuf)
{
    int r = blockIdx.x;            // proto row 0..63
    int tid = threadIdx.x;
    __shared__ float prow[DM];
    for (int i = tid; i < DM; i += 256) prow[i] = protos[r * DM + i];
    __syncthreads();
    for (int j = tid; j < DM; j += 256) {
        float aK = bk[j], aV = bv[j];
        for (int d = 0; d < DM; ++d) {
            float p = prow[d];
            aK += p * wk[d * DM + j];
            aV += p * wv[d * DM + j];
        }
        kt[j * NP + r]   = aK;     // transposed
        vbuf[r * DM + j] = aV;     // row-major
    }
}

// ---------------------------------------------------------------------------
// Kernel 2: fused per-row pipeline, restructured for weight reuse.
// Key change vs prev round: every weight element fetched from L2 is used for
// ALL 15 tokens (45 register accumulators per thread), and kt/vbuf are
// streamed exactly once per block (wave==head). L2 traffic 217GB -> ~15GB.
// LDS: pe 7.5K + qr 45K + sc 15K + small = ~69KB -> 2 blocks/CU.
// ---------------------------------------------------------------------------
__global__ __launch_bounds__(256) void row_kernel(
    const float* __restrict__ state,
    const float* __restrict__ w_scalar, const float* __restrict__ b_scalar,
    const float* __restrict__ w_patch,  const float* __restrict__ b_patch,
    const float* __restrict__ feat_emb,
    const float* __restrict__ pn_g, const float* __restrict__ pn_b,
    const float* __restrict__ wq, const float* __restrict__ bq,
    const float* __restrict__ wp, const float* __restrict__ bp,
    const float* __restrict__ wo, const float* __restrict__ bo,
    const float* __restrict__ on_g, const float* __restrict__ on_b,
    const float* __restrict__ kt, const float* __restrict__ vbuf,
    float* __restrict__ out)
{
    int n   = blockIdx.x;
    int tid = threadIdx.x;
    int wid = tid >> 6, lane = tid & 63;

    __shared__ float pe[NTOK][DP];     // post-LN patch embedding
    __shared__ float qr[NTOK][DM];     // q, overwritten in-place by rep
    __shared__ float sc[NH][NTOK][NP]; // attention weights
    __shared__ float srow[36];
    __shared__ float red[16];

    // ---- load state row --------------------------------------------------
    if (tid < 36) srow[tid] = state[n * 36 + tid];
    __syncthreads();

    // ---- build pe (15 tokens x 128) --------------------------------------
    for (int idx = tid; idx < NTOK * DP; idx += 256) {
        int t = idx / DP, d = idx % DP;
        float val;
        if (t == 0) {
            val = srow[5]  * w_scalar[0 * DP + d] + b_scalar[0 * DP + d] + feat_emb[0 * DP + d];
        } else if (t == 1) {
            val = srow[11] * w_scalar[1 * DP + d] + b_scalar[1 * DP + d] + feat_emb[1 * DP + d];
        } else if (t == 14) {
            val = srow[35] * w_scalar[2 * DP + d] + b_scalar[2 * DP + d] + feat_emb[5 * DP + d];
        } else {
            int f = (t - 2) / 4;
            int k = (t - 2) % 4;
            const float* pr = &srow[(2 + f) * 6];
            float acc = b_patch[f * DP + d] + feat_emb[(2 + f) * DP + d];
            for (int p = 0; p < 3; ++p) acc += pr[k + p] * w_patch[(f * 3 + p) * DP + d];
            val = acc;
        }
        pe[t][d] = val;
    }
    __syncthreads();

    // ---- LayerNorm(pe) over 128: 16 threads per token --------------------
    {
        int tk = tid >> 4, ln = tid & 15;
        if (tk < NTOK) {
            float s = 0.f, s2 = 0.f;
            for (int d = ln; d < DP; d += 16) { float x = pe[tk][d]; s += x; s2 += x * x; }
            for (int off = 8; off; off >>= 1) {
                s  += __shfl_xor(s,  off, 64);
                s2 += __shfl_xor(s2, off, 64);
            }
            float m   = s / DP;
            float var = s2 / DP - m * m;
            float rin = 1.0f / sqrtf(var + EPSF);
            for (int d = ln; d < DP; d += 16)
                pe[tk][d] = (pe[tk][d] - m) * rin * pn_g[d] + pn_b[d];
        }
    }
    __syncthreads();

    const int j0 = tid, j1 = tid + 256, j2 = tid + 512;

    // ---- q = pe @ wq + bq : each wq element used for all 15 tokens -------
    {
        float acc0[NTOK], acc1[NTOK], acc2[NTOK];
        #pragma unroll
        for (int t = 0; t < NTOK; ++t) { acc0[t] = 0.f; acc1[t] = 0.f; acc2[t] = 0.f; }
        #pragma unroll 2
        for (int d = 0; d < DP; ++d) {
            float w0 = wq[d * DM + j0], w1 = wq[d * DM + j1], w2 = wq[d * DM + j2];
            #pragma unroll
            for (int t = 0; t < NTOK; ++t) {
                float p = pe[t][d];
                acc0[t] += p * w0; acc1[t] += p * w1; acc2[t] += p * w2;
            }
        }
        float b0 = bq[j0], b1 = bq[j1], b2 = bq[j2];
        #pragma unroll
        for (int t = 0; t < NTOK; ++t) {
            qr[t][j0] = acc0[t] + b0;
            qr[t][j1] = acc1[t] + b1;
            qr[t][j2] = acc2[t] + b2;
        }
    }
    __syncthreads();

    // ---- attention: wave == head; kt/vbuf streamed exactly once ----------
    {
        const int h = wid;                       // 4 waves, 4 heads
        const float scale = 0.07216878364870323f; // 1/sqrt(192)

        // scores: stream kt_h once, accumulate all 15 tokens
        float s[NTOK];
        #pragma unroll
        for (int t = 0; t < NTOK; ++t) s[t] = 0.f;
        const float* kth = kt + (size_t)h * HD * NP;
        #pragma unroll 2
        for (int d = 0; d < HD; ++d) {
            float kc = kth[d * NP + lane];
            #pragma unroll
            for (int t = 0; t < NTOK; ++t) s[t] += qr[t][h * HD + d] * kc;
        }
        // softmax over lanes (p) per token
        #pragma unroll
        for (int t = 0; t < NTOK; ++t) {
            float v = s[t] * scale;
            float mx = v;
            #pragma unroll
            for (int off = 32; off; off >>= 1) mx = fmaxf(mx, __shfl_xor(mx, off, 64));
            float e = __expf(v - mx);
            float sum = e;
            #pragma unroll
            for (int off = 32; off; off >>= 1) sum += __shfl_xor(sum, off, 64);
            sc[h][t][lane] = e / sum;
        }
        // rep: stream v_h once, accumulate all 15 tokens
        float r0[NTOK], r1[NTOK], r2[NTOK];
        #pragma unroll
        for (int t = 0; t < NTOK; ++t) { r0[t] = 0.f; r1[t] = 0.f; r2[t] = 0.f; }
        const float* vh = vbuf + h * HD;
        #pragma unroll 2
        for (int p = 0; p < NP; ++p) {
            float v0 = vh[p * DM + lane];
            float v1 = vh[p * DM + lane + 64];
            float v2 = vh[p * DM + lane + 128];
            #pragma unroll
            for (int t = 0; t < NTOK; ++t) {
                float a = sc[h][t][p];
                r0[t] += a * v0; r1[t] += a * v1; r2[t] += a * v2;
            }
        }
        #pragma unroll
        for (int t = 0; t < NTOK; ++t) {
            qr[t][h * HD + lane]       = r0[t];
            qr[t][h * HD + lane + 64]  = r1[t];
            qr[t][h * HD + lane + 128] = r2[t];
        }
    }
    __syncthreads();

    // ---- out = LN(rep @ wo + bo + pe @ wp + bp): wo read ONCE per block --
    {
        float a0[NTOK], a1[NTOK], a2[NTOK];
        {
            float t0 = bo[j0] + bp[j0], t1 = bo[j1] + bp[j1], t2 = bo[j2] + bp[j2];
            #pragma unroll
            for (int t = 0; t < NTOK; ++t) { a0[t] = t0; a1[t] = t1; a2[t] = t2; }
        }
        #pragma unroll 2
        for (int dd = 0; dd < DM; ++dd) {
            float w0 = wo[dd * DM + j0], w1 = wo[dd * DM + j1], w2 = wo[dd * DM + j2];
            #pragma unroll
            for (int t = 0; t < NTOK; ++t) {
                float r = qr[t][dd];
                a0[t] += r * w0; a1[t] += r * w1; a2[t] += r * w2;
            }
        }
        #pragma unroll 2
        for (int d = 0; d < DP; ++d) {
            float w0 = wp[d * DM + j0], w1 = wp[d * DM + j1], w2 = wp[d * DM + j2];
            #pragma unroll
            for (int t = 0; t < NTOK; ++t) {
                float p = pe[t][d];
                a0[t] += p * w0; a1[t] += p * w1; a2[t] += p * w2;
            }
        }
        float g0  = on_g[j0], g1  = on_g[j1], g2  = on_g[j2];
        float ob0 = on_b[j0], ob1 = on_b[j1], ob2 = on_b[j2];
        #pragma unroll
        for (int t = 0; t < NTOK; ++t) {
            float s  = a0[t] + a1[t] + a2[t];
            float s2 = a0[t] * a0[t] + a1[t] * a1[t] + a2[t] * a2[t];
            #pragma unroll
            for (int off = 32; off; off >>= 1) {
                s  += __shfl_xor(s,  off, 64);
                s2 += __shfl_xor(s2, off, 64);
            }
            if (lane == 0) { red[wid] = s; red[8 + wid] = s2; }
            __syncthreads();
            float ts  = red[0] + red[1] + red[2] + red[3];
            float ts2 = red[8] + red[9] + red[10] + red[11];
            float m   = ts / DM;
            float var = ts2 / DM - m * m;
            float rin = 1.0f / sqrtf(var + EPSF);
            float* orow = &out[((size_t)n * NTOK + t) * DM];
            orow[j0] = (a0[t] - m) * rin * g0 + ob0;
            orow[j1] = (a1[t] - m) * rin * g1 + ob1;
            orow[j2] = (a2[t] - m) * rin * g2 + ob2;
            __syncthreads();
        }
    }
}

extern "C" void kernel_launch(void* const* d_in, const int* in_sizes, int n_in,
                              void* d_out, int out_size, void* d_ws, size_t ws_size,
                              hipStream_t stream) {
    const float* state    = (const float*)d_in[0];
    const float* w_scalar = (const float*)d_in[1];
    const float* b_scalar = (const float*)d_in[2];
    const float* w_patch  = (const float*)d_in[3];
    const float* b_patch  = (const float*)d_in[4];
    const float* feat_emb = (const float*)d_in[5];
    const float* pn_g     = (const float*)d_in[6];
    const float* pn_b     = (const float*)d_in[7];
    const float* wq       = (const float*)d_in[8];
    const float* bq       = (const float*)d_in[9];
    const float* wk       = (const float*)d_in[10];
    const float* bk       = (const float*)d_in[11];
    const float* wv       = (const float*)d_in[12];
    const float* bv       = (const float*)d_in[13];
    const float* wp       = (const float*)d_in[14];
    const float* bp       = (const float*)d_in[15];
    const float* wo       = (const float*)d_in[16];
    const float* bo       = (const float*)d_in[17];
    const float* on_g     = (const float*)d_in[18];
    const float* on_b     = (const float*)d_in[19];
    const float* protos   = (const float*)d_in[20];
    float* out  = (float*)d_out;
    float* kt   = (float*)d_ws;           // 768*64 floats
    float* vbuf = kt + DM * NP;           // 64*768 floats

    int N = in_sizes[0] / 36;             // B*T rows

    hipLaunchKernelGGL(kv_kernel, dim3(NP), dim3(256), 0, stream,
                       protos, wk, bk, wv, bv, kt, vbuf);
    hipLaunchKernelGGL(row_kernel, dim3(N), dim3(256), 0, stream,
                       state, w_scalar, b_scalar, w_patch, b_patch, feat_emb,
                       pn_g, pn_b, wq, bq, wp, bp, wo, bo, on_g, on_b,
                       kt, vbuf, out);
}

// Round 6
// 1136.027 us; speedup vs baseline: 5.8888x; 1.8151x over previous
//
#include <hip/hip_runtime.h>

#define NTOK 15
#define DP   128
#define DM   768
#define NH   4
#define HD   192
#define NP   64
#define EPSF 1e-5f
#define QSTR 772   // qr row stride in floats (772%32=4 -> bank-conflict-free rows)

typedef __attribute__((ext_vector_type(8))) short bf16x8;   // 8 bf16 = 4 VGPR
typedef __attribute__((ext_vector_type(4))) float f32x4;

__device__ __forceinline__ unsigned short f2bf(float x) {
    unsigned u = __float_as_uint(x);
    u = (u + 0x7FFF + ((u >> 16) & 1)) >> 16;   // RNE
    return (unsigned short)u;
}
// swizzled LDS byte addresses for MFMA A-operand tiles (row stride 1536B / 256B)
__device__ __forceinline__ int swzA(int row, int b) { return row * 1536 + (b ^ ((row & 7) << 4)); }
__device__ __forceinline__ int swzP(int row, int b) { return row * 256  + (b ^ ((row & 7) << 4)); }

// ---------------------------------------------------------------------------
// Prep: dst[N][K] bf16 = transpose(src[K][N] f32)
// ---------------------------------------------------------------------------
__global__ __launch_bounds__(256) void wT_bf16_kernel(
    const float* __restrict__ src, unsigned short* __restrict__ dst, int K, int N)
{
    int idx = blockIdx.x * 256 + threadIdx.x;
    if (idx >= K * N) return;
    int n = idx / K, k = idx - n * K;
    dst[idx] = f2bf(src[k * N + n]);
}

// ---------------------------------------------------------------------------
// K^T and V from protos (unchanged, verified).
// ---------------------------------------------------------------------------
__global__ __launch_bounds__(256) void kv_kernel(
    const float* __restrict__ protos,
    const float* __restrict__ wk, const float* __restrict__ bk,
    const float* __restrict__ wv, const float* __restrict__ bv,
    float* __restrict__ kt, float* __restrict__ vbuf)
{
    int r = blockIdx.x;
    int tid = threadIdx.x;
    __shared__ float prow[DM];
    for (int i = tid; i < DM; i += 256) prow[i] = protos[r * DM + i];
    __syncthreads();
    for (int j = tid; j < DM; j += 256) {
        float aK = bk[j], aV = bv[j];
        for (int d = 0; d < DM; ++d) {
            float p = prow[d];
            aK += p * wk[d * DM + j];
            aV += p * wv[d * DM + j];
        }
        kt[j * NP + r]   = aK;
        vbuf[r * DM + j] = aV;
    }
}

// ---------------------------------------------------------------------------
// Fused per-row pipeline. MFMA for q-GEMM and out-GEMM; f32 attention.
// LDS regions: regA (49408B) = qr f32 -> (rep bf16 A-tile) ; pe ; sc ; pebf.
// Total ~77.2KB -> 2 blocks/CU.
// ---------------------------------------------------------------------------
__global__ __launch_bounds__(256, 2) void row_kernel(
    const float* __restrict__ state,
    const float* __restrict__ w_scalar, const float* __restrict__ b_scalar,
    const float* __restrict__ w_patch,  const float* __restrict__ b_patch,
    const float* __restrict__ feat_emb,
    const float* __restrict__ pn_g, const float* __restrict__ pn_b,
    const unsigned short* __restrict__ wqT, const float* __restrict__ bq,
    const unsigned short* __restrict__ wpT, const float* __restrict__ bp,
    const unsigned short* __restrict__ woT, const float* __restrict__ bo,
    const float* __restrict__ on_g, const float* __restrict__ on_b,
    const float* __restrict__ kt, const float* __restrict__ vbuf,
    float* __restrict__ out)
{
    int n   = blockIdx.x;
    int tid = threadIdx.x;
    int wid = tid >> 6, lane = tid & 63;
    int kg  = lane >> 4, lr = lane & 15;   // MFMA k-group / row-or-col-in-tile

    __shared__ __align__(16) char regA[16 * QSTR * 4];  // 49408B
    __shared__ float pe[NTOK][DP];
    __shared__ float sc[NH][NTOK][NP];
    __shared__ __align__(16) char pebf[4096];
    __shared__ float srow[36];
    __shared__ float redS[4][16], redS2[4][16];

    float* qr = (float*)regA;   // [16][QSTR] f32 view (q, dead after attention)

    // ---- load state row --------------------------------------------------
    if (tid < 36) srow[tid] = state[n * 36 + tid];
    __syncthreads();

    // ---- build pe (15 tokens x 128) --------------------------------------
    for (int idx = tid; idx < NTOK * DP; idx += 256) {
        int t = idx >> 7, d = idx & 127;
        float val;
        if (t == 0) {
            val = srow[5]  * w_scalar[0 * DP + d] + b_scalar[0 * DP + d] + feat_emb[0 * DP + d];
        } else if (t == 1) {
            val = srow[11] * w_scalar[1 * DP + d] + b_scalar[1 * DP + d] + feat_emb[1 * DP + d];
        } else if (t == 14) {
            val = srow[35] * w_scalar[2 * DP + d] + b_scalar[2 * DP + d] + feat_emb[5 * DP + d];
        } else {
            int f = (t - 2) / 4;
            int k = (t - 2) % 4;
            const float* pr = &srow[(2 + f) * 6];
            float acc = b_patch[f * DP + d] + feat_emb[(2 + f) * DP + d];
            for (int p = 0; p < 3; ++p) acc += pr[k + p] * w_patch[(f * 3 + p) * DP + d];
            val = acc;
        }
        pe[t][d] = val;
    }
    __syncthreads();

    // ---- LayerNorm(pe): 16 threads per token -----------------------------
    {
        int tk = tid >> 4, ln = tid & 15;
        if (tk < NTOK) {
            float s = 0.f, s2 = 0.f;
            for (int d = ln; d < DP; d += 16) { float x = pe[tk][d]; s += x; s2 += x * x; }
            for (int off = 8; off; off >>= 1) {
                s  += __shfl_xor(s,  off, 64);
                s2 += __shfl_xor(s2, off, 64);
            }
            float m   = s / DP;
            float var = s2 / DP - m * m;
            float rin = 1.0f / sqrtf(var + EPSF);
            for (int d = ln; d < DP; d += 16)
                pe[tk][d] = (pe[tk][d] - m) * rin * pn_g[d] + pn_b[d];
        }
    }
    __syncthreads();

    // ---- pe -> bf16 A-tile (swizzled) ------------------------------------
    for (int idx = tid; idx < NTOK * DP; idx += 256) {
        int t = idx >> 7, c = idx & 127;
        *(unsigned short*)(pebf + swzP(t, c * 2)) = f2bf(pe[t][c]);
    }
    __syncthreads();

    // ---- q = pe @ wq + bq via MFMA; wave covers cols [wid*192, +192) -----
    {
        bf16x8 ap[4];
        #pragma unroll
        for (int kk = 0; kk < 4; ++kk)
            ap[kk] = *(const bf16x8*)(pebf + swzP(lr, kk * 64 + kg * 16));
        #pragma unroll
        for (int nt = 0; nt < 12; ++nt) {
            int n0 = wid * 192 + nt * 16;
            f32x4 acc = {0.f, 0.f, 0.f, 0.f};
            #pragma unroll
            for (int kk = 0; kk < 4; ++kk) {
                bf16x8 b = *(const bf16x8*)(wqT + ((n0 + lr) * DP + kk * 32 + kg * 8));
                acc = __builtin_amdgcn_mfma_f32_16x16x32_bf16(ap[kk], b, acc, 0, 0, 0);
            }
            float bqv = bq[n0 + lr];
            #pragma unroll
            for (int r = 0; r < 4; ++r)
                qr[(kg * 4 + r) * QSTR + n0 + lr] = acc[r] + bqv;
        }
    }
    __syncthreads();

    // ---- attention (f32): wave == head; rep kept in registers ------------
    float r0[NTOK], r1[NTOK], r2[NTOK];
    {
        const int h = wid;
        const float scale = 0.07216878364870323f;   // 1/sqrt(192)
        float s[NTOK];
        #pragma unroll
        for (int t = 0; t < NTOK; ++t) s[t] = 0.f;
        const float* kth = kt + (size_t)h * HD * NP;
        #pragma unroll 2
        for (int d = 0; d < HD; ++d) {
            float kc = kth[d * NP + lane];
            #pragma unroll
            for (int t = 0; t < NTOK; ++t) s[t] += qr[t * QSTR + h * HD + d] * kc;
        }
        #pragma unroll
        for (int t = 0; t < NTOK; ++t) {
            float v = s[t] * scale;
            float mx = v;
            #pragma unroll
            for (int off = 32; off; off >>= 1) mx = fmaxf(mx, __shfl_xor(mx, off, 64));
            float e = __expf(v - mx);
            float sum = e;
            #pragma unroll
            for (int off = 32; off; off >>= 1) sum += __shfl_xor(sum, off, 64);
            sc[h][t][lane] = e / sum;
        }
        #pragma unroll
        for (int t = 0; t < NTOK; ++t) { r0[t] = 0.f; r1[t] = 0.f; r2[t] = 0.f; }
        const float* vh = vbuf + h * HD;
        #pragma unroll 2
        for (int p = 0; p < NP; ++p) {
            float v0 = vh[p * DM + lane];
            float v1 = vh[p * DM + lane + 64];
            float v2 = vh[p * DM + lane + 128];
            #pragma unroll
            for (int t = 0; t < NTOK; ++t) {
                float a = sc[h][t][p];
                r0[t] += a * v0; r1[t] += a * v1; r2[t] += a * v2;
            }
        }
    }
    __syncthreads();   // all q reads done; regA reusable

    // ---- rep -> bf16 A-tile in regA (swizzled) ---------------------------
    {
        const int h = wid;
        #pragma unroll
        for (int t = 0; t < NTOK; ++t) {
            int c = h * HD + lane;
            *(unsigned short*)(regA + swzA(t, c * 2))         = f2bf(r0[t]);
            *(unsigned short*)(regA + swzA(t, (c + 64) * 2))  = f2bf(r1[t]);
            *(unsigned short*)(regA + swzA(t, (c + 128) * 2)) = f2bf(r2[t]);
        }
    }
    __syncthreads();

    // ---- out = LN(rep@wo + pe@wp + bo + bp) via MFMA ---------------------
    {
        bf16x8 aw[24], apf[4];
        #pragma unroll
        for (int kk = 0; kk < 24; ++kk)
            aw[kk] = *(const bf16x8*)(regA + swzA(lr, kk * 64 + kg * 16));
        #pragma unroll
        for (int kk = 0; kk < 4; ++kk)
            apf[kk] = *(const bf16x8*)(pebf + swzP(lr, kk * 64 + kg * 16));

        f32x4 acc[12];
        #pragma unroll
        for (int nt = 0; nt < 12; ++nt) {
            int n0 = wid * 192 + nt * 16;
            f32x4 a = {0.f, 0.f, 0.f, 0.f};
            #pragma unroll
            for (int kk = 0; kk < 24; ++kk) {
                bf16x8 b = *(const bf16x8*)(woT + ((size_t)(n0 + lr) * DM + kk * 32 + kg * 8));
                a = __builtin_amdgcn_mfma_f32_16x16x32_bf16(aw[kk], b, a, 0, 0, 0);
            }
            #pragma unroll
            for (int kk = 0; kk < 4; ++kk) {
                bf16x8 b = *(const bf16x8*)(wpT + ((n0 + lr) * DP + kk * 32 + kg * 8));
                a = __builtin_amdgcn_mfma_f32_16x16x32_bf16(apf[kk], b, a, 0, 0, 0);
            }
            float bias = bo[n0 + lr] + bp[n0 + lr];
            #pragma unroll
            for (int r = 0; r < 4; ++r) a[r] += bias;
            acc[nt] = a;
        }

        // LN stats on C-fragment layout: token t=(kg*4+r), col=n0+lr
        float sA[4] = {0.f, 0.f, 0.f, 0.f}, qA[4] = {0.f, 0.f, 0.f, 0.f};
        #pragma unroll
        for (int nt = 0; nt < 12; ++nt) {
            #pragma unroll
            for (int r = 0; r < 4; ++r) { float v = acc[nt][r]; sA[r] += v; qA[r] += v * v; }
        }
        #pragma unroll
        for (int off = 8; off; off >>= 1) {
            #pragma unroll
            for (int r = 0; r < 4; ++r) {
                sA[r] += __shfl_xor(sA[r], off, 64);
                qA[r] += __shfl_xor(qA[r], off, 64);
            }
        }
        if (lr == 0) {
            #pragma unroll
            for (int r = 0; r < 4; ++r) {
                redS [wid][kg * 4 + r] = sA[r];
                redS2[wid][kg * 4 + r] = qA[r];
            }
        }
        __syncthreads();
        float mArr[4], riArr[4];
        #pragma unroll
        for (int r = 0; r < 4; ++r) {
            int t = kg * 4 + r;
            float ts = redS [0][t] + redS [1][t] + redS [2][t] + redS [3][t];
            float tq = redS2[0][t] + redS2[1][t] + redS2[2][t] + redS2[3][t];
            float mm = ts / DM;
            float var = tq / DM - mm * mm;
            mArr[r]  = mm;
            riArr[r] = 1.0f / sqrtf(var + EPSF);
        }
        float* ob = out + (size_t)n * NTOK * DM;
        #pragma unroll
        for (int nt = 0; nt < 12; ++nt) {
            int n0  = wid * 192 + nt * 16;
            int col = n0 + lr;
            float g = on_g[col], bb = on_b[col];
            #pragma unroll
            for (int r = 0; r < 4; ++r) {
                int t = kg * 4 + r;
                if (t < NTOK)
                    ob[t * DM + col] = (acc[nt][r] - mArr[r]) * riArr[r] * g + bb;
            }
        }
    }
}

extern "C" void kernel_launch(void* const* d_in, const int* in_sizes, int n_in,
                              void* d_out, int out_size, void* d_ws, size_t ws_size,
                              hipStream_t stream) {
    const float* state    = (const float*)d_in[0];
    const float* w_scalar = (const float*)d_in[1];
    const float* b_scalar = (const float*)d_in[2];
    const float* w_patch  = (const float*)d_in[3];
    const float* b_patch  = (const float*)d_in[4];
    const float* feat_emb = (const float*)d_in[5];
    const float* pn_g     = (const float*)d_in[6];
    const float* pn_b     = (const float*)d_in[7];
    const float* wq       = (const float*)d_in[8];
    const float* bq       = (const float*)d_in[9];
    const float* wk       = (const float*)d_in[10];
    const float* bk       = (const float*)d_in[11];
    const float* wv       = (const float*)d_in[12];
    const float* bv       = (const float*)d_in[13];
    const float* wp       = (const float*)d_in[14];
    const float* bp       = (const float*)d_in[15];
    const float* wo       = (const float*)d_in[16];
    const float* bo       = (const float*)d_in[17];
    const float* on_g     = (const float*)d_in[18];
    const float* on_b     = (const float*)d_in[19];
    const float* protos   = (const float*)d_in[20];
    float* out = (float*)d_out;

    float* kt   = (float*)d_ws;                       // 49152 f32
    float* vbuf = kt + DM * NP;                       // 49152 f32
    unsigned short* wqT = (unsigned short*)(vbuf + DM * NP);  // [768][128]
    unsigned short* woT = wqT + DM * DP;                      // [768][768]
    unsigned short* wpT = woT + DM * DM;                      // [768][128]

    int N = in_sizes[0] / 36;

    hipLaunchKernelGGL(wT_bf16_kernel, dim3((DP * DM + 255) / 256), dim3(256), 0, stream, wq, wqT, DP, DM);
    hipLaunchKernelGGL(wT_bf16_kernel, dim3((DM * DM + 255) / 256), dim3(256), 0, stream, wo, woT, DM, DM);
    hipLaunchKernelGGL(wT_bf16_kernel, dim3((DP * DM + 255) / 256), dim3(256), 0, stream, wp, wpT, DP, DM);
    hipLaunchKernelGGL(kv_kernel, dim3(NP), dim3(256), 0, stream,
                       protos, wk, bk, wv, bv, kt, vbuf);
    hipLaunchKernelGGL(row_kernel, dim3(N), dim3(256), 0, stream,
                       state, w_scalar, b_scalar, w_patch, b_patch, feat_emb,
                       pn_g, pn_b, wqT, bq, wpT, bp, woT, bo, on_g, on_b,
                       kt, vbuf, out);
}

// Round 7
// 900.463 us; speedup vs baseline: 7.4294x; 1.2616x over previous
//
#include <hip/hip_runtime.h>

#define NTOK 15
#define DP   128
#define DM   768
#define NH   4
#define HD   192
#define NP   64
#define EPSF 1e-5f
#define QPAD 200   // qbuf row stride (bf16): 400B, 16B-aligned, rows offset 4 banks
#define PPAD 72    // pbuf row stride (bf16): 144B, 16B-aligned

typedef __attribute__((ext_vector_type(8))) short bf16x8;   // 8 bf16 = 4 VGPR
typedef __attribute__((ext_vector_type(4))) float f32x4;

__device__ __forceinline__ unsigned short f2bf(float x) {
    unsigned u = __float_as_uint(x);
    u = (u + 0x7FFF + ((u >> 16) & 1)) >> 16;   // RNE
    return (unsigned short)u;
}
// swizzled LDS byte addresses for MFMA A-operand tiles
__device__ __forceinline__ int swzA(int row, int b) { return row * 1536 + (b ^ ((row & 7) << 4)); }
__device__ __forceinline__ int swzP(int row, int b) { return row * 256  + (b ^ ((row & 7) << 4)); }

// ---------------------------------------------------------------------------
// Prep: dst[N][K] bf16 = transpose(src[K][N] f32)
// ---------------------------------------------------------------------------
__global__ __launch_bounds__(256) void wT_bf16_kernel(
    const float* __restrict__ src, unsigned short* __restrict__ dst, int K, int N)
{
    int idx = blockIdx.x * 256 + threadIdx.x;
    if (idx >= K * N) return;
    int n = idx / K, k = idx - n * K;
    dst[idx] = f2bf(src[k * N + n]);
}

// ---------------------------------------------------------------------------
// K (bf16, pre-scaled, [h][p][d]) and V^T (bf16, [j][p]) from protos.
// ---------------------------------------------------------------------------
__global__ __launch_bounds__(256) void kv_kernel(
    const float* __restrict__ protos,
    const float* __restrict__ wk, const float* __restrict__ bk,
    const float* __restrict__ wv, const float* __restrict__ bv,
    unsigned short* __restrict__ kbf, unsigned short* __restrict__ vtbf)
{
    int r = blockIdx.x;            // proto 0..63
    int tid = threadIdx.x;
    __shared__ float prow[DM];
    for (int i = tid; i < DM; i += 256) prow[i] = protos[r * DM + i];
    __syncthreads();
    const float scale = 0.07216878364870323f;   // 1/sqrt(192)
    for (int j = tid; j < DM; j += 256) {
        float aK = bk[j], aV = bv[j];
        for (int d = 0; d < DM; ++d) {
            float p = prow[d];
            aK += p * wk[d * DM + j];
            aV += p * wv[d * DM + j];
        }
        int h = j / HD, d = j % HD;
        kbf[(h * NP + r) * HD + d] = f2bf(aK * scale);
        vtbf[j * NP + r]           = f2bf(aV);
    }
}

// ---------------------------------------------------------------------------
// Fused per-row pipeline — MFMA everywhere except pe-build/LN.
// LDS: regA 24K + pe 7.5K + pebf 4K + qbuf 25.6K + pbuf 9.2K + misc ~ 71.8KB
// -> 2 blocks/CU.
// ---------------------------------------------------------------------------
__global__ __launch_bounds__(256, 2) void row_kernel(
    const float* __restrict__ state,
    const float* __restrict__ w_scalar, const float* __restrict__ b_scalar,
    const float* __restrict__ w_patch,  const float* __restrict__ b_patch,
    const float* __restrict__ feat_emb,
    const float* __restrict__ pn_g, const float* __restrict__ pn_b,
    const unsigned short* __restrict__ wqT, const float* __restrict__ bq,
    const unsigned short* __restrict__ wpT, const float* __restrict__ bp,
    const unsigned short* __restrict__ woT, const float* __restrict__ bo,
    const float* __restrict__ on_g, const float* __restrict__ on_b,
    const unsigned short* __restrict__ kbf, const unsigned short* __restrict__ vtbf,
    float* __restrict__ out)
{
    int n   = blockIdx.x;
    int tid = threadIdx.x;
    int wid = tid >> 6, lane = tid & 63;
    int kg  = lane >> 4, lr = lane & 15;

    __shared__ __align__(16) char regA[16 * 1536];          // rep bf16 A-tile (swizzled)
    __shared__ float pe[NTOK][DP];
    __shared__ __align__(16) char pebf[4096];               // pe bf16 A-tile (swizzled)
    __shared__ __align__(16) unsigned short qbuf[NH][16 * QPAD];
    __shared__ __align__(16) unsigned short pbuf[NH][16 * PPAD];
    __shared__ float srow[36];
    __shared__ float redS[4][16], redS2[4][16];

    // ---- load state row --------------------------------------------------
    if (tid < 36) srow[tid] = state[n * 36 + tid];
    __syncthreads();

    // ---- build pe (15 tokens x 128) --------------------------------------
    for (int idx = tid; idx < NTOK * DP; idx += 256) {
        int t = idx >> 7, d = idx & 127;
        float val;
        if (t == 0) {
            val = srow[5]  * w_scalar[0 * DP + d] + b_scalar[0 * DP + d] + feat_emb[0 * DP + d];
        } else if (t == 1) {
            val = srow[11] * w_scalar[1 * DP + d] + b_scalar[1 * DP + d] + feat_emb[1 * DP + d];
        } else if (t == 14) {
            val = srow[35] * w_scalar[2 * DP + d] + b_scalar[2 * DP + d] + feat_emb[5 * DP + d];
        } else {
            int f = (t - 2) / 4;
            int k = (t - 2) % 4;
            const float* pr = &srow[(2 + f) * 6];
            float acc = b_patch[f * DP + d] + feat_emb[(2 + f) * DP + d];
            for (int p = 0; p < 3; ++p) acc += pr[k + p] * w_patch[(f * 3 + p) * DP + d];
            val = acc;
        }
        pe[t][d] = val;
    }
    __syncthreads();

    // ---- LayerNorm(pe): 16 threads per token -----------------------------
    {
        int tk = tid >> 4, ln = tid & 15;
        if (tk < NTOK) {
            float s = 0.f, s2 = 0.f;
            for (int d = ln; d < DP; d += 16) { float x = pe[tk][d]; s += x; s2 += x * x; }
            for (int off = 8; off; off >>= 1) {
                s  += __shfl_xor(s,  off, 64);
                s2 += __shfl_xor(s2, off, 64);
            }
            float m   = s / DP;
            float var = s2 / DP - m * m;
            float rin = 1.0f / sqrtf(var + EPSF);
            for (int d = ln; d < DP; d += 16)
                pe[tk][d] = (pe[tk][d] - m) * rin * pn_g[d] + pn_b[d];
        }
    }
    __syncthreads();

    // ---- pe -> bf16 A-tile (swizzled); zero pad row 15 -------------------
    for (int idx = tid; idx < NTOK * DP; idx += 256) {
        int t = idx >> 7, c = idx & 127;
        *(unsigned short*)(pebf + swzP(t, c * 2)) = f2bf(pe[t][c]);
    }
    if (tid < DP) *(unsigned short*)(pebf + swzP(15, tid * 2)) = 0;
    __syncthreads();

    // ---- q = pe @ wq + bq via MFMA -> qbuf bf16 (wave-private) -----------
    {
        bf16x8 ap[4];
        #pragma unroll
        for (int kk = 0; kk < 4; ++kk)
            ap[kk] = *(const bf16x8*)(pebf + swzP(lr, kk * 64 + kg * 16));
        #pragma unroll
        for (int nt = 0; nt < 12; ++nt) {
            int n0 = wid * 192 + nt * 16;
            f32x4 acc = {0.f, 0.f, 0.f, 0.f};
            #pragma unroll
            for (int kk = 0; kk < 4; ++kk) {
                bf16x8 b = *(const bf16x8*)(wqT + ((n0 + lr) * DP + kk * 32 + kg * 8));
                acc = __builtin_amdgcn_mfma_f32_16x16x32_bf16(ap[kk], b, acc, 0, 0, 0);
            }
            float bqv = bq[n0 + lr];
            #pragma unroll
            for (int r = 0; r < 4; ++r)
                qbuf[wid][(kg * 4 + r) * QPAD + nt * 16 + lr] = f2bf(acc[r] + bqv);
        }
    }
    // qbuf/pbuf are wave-private: no __syncthreads needed through PV.

    // ---- scores^T = K_scaled @ q^T  (M=64 p, N=16 t, K=192) --------------
    f32x4 sacc[4];
    {
        const unsigned short* kbh = kbf + (size_t)wid * NP * HD;
        bf16x8 qB[6];
        #pragma unroll
        for (int kk = 0; kk < 6; ++kk)
            qB[kk] = *(const bf16x8*)(&qbuf[wid][lr * QPAD + kk * 32 + kg * 8]);
        #pragma unroll
        for (int Mt = 0; Mt < 4; ++Mt) {
            f32x4 a = {0.f, 0.f, 0.f, 0.f};
            #pragma unroll
            for (int kk = 0; kk < 6; ++kk) {
                bf16x8 af = *(const bf16x8*)(kbh + (Mt * 16 + lr) * HD + kk * 32 + kg * 8);
                a = __builtin_amdgcn_mfma_f32_16x16x32_bf16(af, qB[kk], a, 0, 0, 0);
            }
            sacc[Mt] = a;
        }
    }
    // ---- softmax over p (rows of scores^T), per column t=lr --------------
    {
        float mx = -3.4e38f;
        #pragma unroll
        for (int Mt = 0; Mt < 4; ++Mt)
            #pragma unroll
            for (int r = 0; r < 4; ++r) mx = fmaxf(mx, sacc[Mt][r]);
        mx = fmaxf(mx, __shfl_xor(mx, 16, 64));
        mx = fmaxf(mx, __shfl_xor(mx, 32, 64));
        float sum = 0.f;
        f32x4 ee[4];
        #pragma unroll
        for (int Mt = 0; Mt < 4; ++Mt)
            #pragma unroll
            for (int r = 0; r < 4; ++r) { float e = __expf(sacc[Mt][r] - mx); ee[Mt][r] = e; sum += e; }
        sum += __shfl_xor(sum, 16, 64);
        sum += __shfl_xor(sum, 32, 64);
        float inv = 1.0f / sum;
        #pragma unroll
        for (int Mt = 0; Mt < 4; ++Mt)
            #pragma unroll
            for (int r = 0; r < 4; ++r)
                pbuf[wid][lr * PPAD + Mt * 16 + kg * 4 + r] = f2bf(ee[Mt][r] * inv);
    }

    // ---- rep = P @ V  (M=16 t, N=192 d, K=64 p) --------------------------
    {
        bf16x8 pA[2];
        #pragma unroll
        for (int kk = 0; kk < 2; ++kk)
            pA[kk] = *(const bf16x8*)(&pbuf[wid][lr * PPAD + kk * 32 + kg * 8]);
        f32x4 racc[12];
        #pragma unroll
        for (int nt = 0; nt < 12; ++nt) {
            int j = wid * 192 + nt * 16 + lr;
            f32x4 a = {0.f, 0.f, 0.f, 0.f};
            #pragma unroll
            for (int kk = 0; kk < 2; ++kk) {
                bf16x8 b = *(const bf16x8*)(vtbf + (size_t)j * NP + kk * 32 + kg * 8);
                a = __builtin_amdgcn_mfma_f32_16x16x32_bf16(pA[kk], b, a, 0, 0, 0);
            }
            racc[nt] = a;
        }
        // rep C-frag -> regA bf16 swizzled (row = token, col = wid*192+nt*16+lr)
        #pragma unroll
        for (int nt = 0; nt < 12; ++nt) {
            int c = wid * 192 + nt * 16 + lr;
            #pragma unroll
            for (int r = 0; r < 4; ++r)
                *(unsigned short*)(regA + swzA(kg * 4 + r, c * 2)) = f2bf(racc[nt][r]);
        }
    }
    __syncthreads();

    // ---- out = LN(rep@wo + pe@wp + bo + bp) via MFMA ---------------------
    {
        bf16x8 aw[24], apf[4];
        #pragma unroll
        for (int kk = 0; kk < 24; ++kk)
            aw[kk] = *(const bf16x8*)(regA + swzA(lr, kk * 64 + kg * 16));
        #pragma unroll
        for (int kk = 0; kk < 4; ++kk)
            apf[kk] = *(const bf16x8*)(pebf + swzP(lr, kk * 64 + kg * 16));

        f32x4 acc[12];
        #pragma unroll
        for (int nt = 0; nt < 12; ++nt) {
            int n0 = wid * 192 + nt * 16;
            f32x4 a = {0.f, 0.f, 0.f, 0.f};
            #pragma unroll
            for (int kk = 0; kk < 24; ++kk) {
                bf16x8 b = *(const bf16x8*)(woT + ((size_t)(n0 + lr) * DM + kk * 32 + kg * 8));
                a = __builtin_amdgcn_mfma_f32_16x16x32_bf16(aw[kk], b, a, 0, 0, 0);
            }
            #pragma unroll
            for (int kk = 0; kk < 4; ++kk) {
                bf16x8 b = *(const bf16x8*)(wpT + ((n0 + lr) * DP + kk * 32 + kg * 8));
                a = __builtin_amdgcn_mfma_f32_16x16x32_bf16(apf[kk], b, a, 0, 0, 0);
            }
            float bias = bo[n0 + lr] + bp[n0 + lr];
            #pragma unroll
            for (int r = 0; r < 4; ++r) a[r] += bias;
            acc[nt] = a;
        }

        // LN stats on C-fragment layout: token t=(kg*4+r), col=n0+lr
        float sA[4] = {0.f, 0.f, 0.f, 0.f}, qA[4] = {0.f, 0.f, 0.f, 0.f};
        #pragma unroll
        for (int nt = 0; nt < 12; ++nt)
            #pragma unroll
            for (int r = 0; r < 4; ++r) { float v = acc[nt][r]; sA[r] += v; qA[r] += v * v; }
        #pragma unroll
        for (int off = 8; off; off >>= 1) {
            #pragma unroll
            for (int r = 0; r < 4; ++r) {
                sA[r] += __shfl_xor(sA[r], off, 64);
                qA[r] += __shfl_xor(qA[r], off, 64);
            }
        }
        if (lr == 0) {
            #pragma unroll
            for (int r = 0; r < 4; ++r) {
                redS [wid][kg * 4 + r] = sA[r];
                redS2[wid][kg * 4 + r] = qA[r];
            }
        }
        __syncthreads();
        float mArr[4], riArr[4];
        #pragma unroll
        for (int r = 0; r < 4; ++r) {
            int t = kg * 4 + r;
            float ts = redS [0][t] + redS [1][t] + redS [2][t] + redS [3][t];
            float tq = redS2[0][t] + redS2[1][t] + redS2[2][t] + redS2[3][t];
            float mm = ts / DM;
            float var = tq / DM - mm * mm;
            mArr[r]  = mm;
            riArr[r] = 1.0f / sqrtf(var + EPSF);
        }
        float* ob = out + (size_t)n * NTOK * DM;
        #pragma unroll
        for (int nt = 0; nt < 12; ++nt) {
            int n0  = wid * 192 + nt * 16;
            int col = n0 + lr;
            float g = on_g[col], bb = on_b[col];
            #pragma unroll
            for (int r = 0; r < 4; ++r) {
                int t = kg * 4 + r;
                if (t < NTOK)
                    ob[t * DM + col] = (acc[nt][r] - mArr[r]) * riArr[r] * g + bb;
            }
        }
    }
}

extern "C" void kernel_launch(void* const* d_in, const int* in_sizes, int n_in,
                              void* d_out, int out_size, void* d_ws, size_t ws_size,
                              hipStream_t stream) {
    const float* state    = (const float*)d_in[0];
    const float* w_scalar = (const float*)d_in[1];
    const float* b_scalar = (const float*)d_in[2];
    const float* w_patch  = (const float*)d_in[3];
    const float* b_patch  = (const float*)d_in[4];
    const float* feat_emb = (const float*)d_in[5];
    const float* pn_g     = (const float*)d_in[6];
    const float* pn_b     = (const float*)d_in[7];
    const float* wq       = (const float*)d_in[8];
    const float* bq       = (const float*)d_in[9];
    const float* wk       = (const float*)d_in[10];
    const float* bk       = (const float*)d_in[11];
    const float* wv       = (const float*)d_in[12];
    const float* bv       = (const float*)d_in[13];
    const float* wp       = (const float*)d_in[14];
    const float* bp       = (const float*)d_in[15];
    const float* wo       = (const float*)d_in[16];
    const float* bo       = (const float*)d_in[17];
    const float* on_g     = (const float*)d_in[18];
    const float* on_b     = (const float*)d_in[19];
    const float* protos   = (const float*)d_in[20];
    float* out = (float*)d_out;

    unsigned short* kbf  = (unsigned short*)d_ws;   // [4][64][192] bf16, pre-scaled
    unsigned short* vtbf = kbf + DM * NP;           // [768][64] bf16
    unsigned short* wqT  = vtbf + DM * NP;          // [768][128] bf16
    unsigned short* woT  = wqT + DM * DP;           // [768][768] bf16
    unsigned short* wpT  = woT + DM * DM;           // [768][128] bf16

    int N = in_sizes[0] / 36;

    hipLaunchKernelGGL(wT_bf16_kernel, dim3((DP * DM + 255) / 256), dim3(256), 0, stream, wq, wqT, DP, DM);
    hipLaunchKernelGGL(wT_bf16_kernel, dim3((DM * DM + 255) / 256), dim3(256), 0, stream, wo, woT, DM, DM);
    hipLaunchKernelGGL(wT_bf16_kernel, dim3((DP * DM + 255) / 256), dim3(256), 0, stream, wp, wpT, DP, DM);
    hipLaunchKernelGGL(kv_kernel, dim3(NP), dim3(256), 0, stream,
                       protos, wk, bk, wv, bv, kbf, vtbf);
    hipLaunchKernelGGL(row_kernel, dim3(N), dim3(256), 0, stream,
                       state, w_scalar, b_scalar, w_patch, b_patch, feat_emb,
                       pn_g, pn_b, wqT, bq, wpT, bp, woT, bo, on_g, on_b,
                       kbf, vtbf, out);
}

// Round 8
// 487.815 us; speedup vs baseline: 13.7140x; 1.8459x over previous
//
#include <hip/hip_runtime.h>

#define NTOK 15
#define DP   128
#define DM   768
#define NH   4
#define HD   192
#define NP   64
#define EPSF 1e-5f
#define RPB  4      // rows per block
#define TPB  512    // 8 waves
#define PPAD 72     // pbuf p-stride (144B rows: 16B-aligned, bank offset 4)

typedef __attribute__((ext_vector_type(8))) short bf16x8;   // 8 bf16 = 4 VGPR
typedef __attribute__((ext_vector_type(4))) float f32x4;

__device__ __forceinline__ unsigned short f2bf(float x) {
    unsigned u = __float_as_uint(x);
    u = (u + 0x7FFF + ((u >> 16) & 1)) >> 16;   // RNE
    return (unsigned short)u;
}
// swizzled LDS byte addresses for MFMA A/B tiles (row stride 1536B / 256B)
__device__ __forceinline__ int swzA(int row, int b) { return row * 1536 + (b ^ ((row & 7) << 4)); }
__device__ __forceinline__ int swzP(int row, int b) { return row * 256  + (b ^ ((row & 7) << 4)); }

// ---------------------------------------------------------------------------
// Prep: dst[N][K] bf16 = transpose(src[K][N] f32)
// ---------------------------------------------------------------------------
__global__ __launch_bounds__(256) void wT_bf16_kernel(
    const float* __restrict__ src, unsigned short* __restrict__ dst, int K, int N)
{
    int idx = blockIdx.x * 256 + threadIdx.x;
    if (idx >= K * N) return;
    int n = idx / K, k = idx - n * K;
    dst[idx] = f2bf(src[k * N + n]);
}

// ---------------------------------------------------------------------------
// K (bf16, pre-scaled, [h][p][d]) and V^T (bf16, [j][p]) from protos.
// ---------------------------------------------------------------------------
__global__ __launch_bounds__(256) void kv_kernel(
    const float* __restrict__ protos,
    const float* __restrict__ wk, const float* __restrict__ bk,
    const float* __restrict__ wv, const float* __restrict__ bv,
    unsigned short* __restrict__ kbf, unsigned short* __restrict__ vtbf)
{
    int r = blockIdx.x;            // proto 0..63
    int tid = threadIdx.x;
    __shared__ float prow[DM];
    for (int i = tid; i < DM; i += 256) prow[i] = protos[r * DM + i];
    __syncthreads();
    const float scale = 0.07216878364870323f;   // 1/sqrt(192)
    for (int j = tid; j < DM; j += 256) {
        float aK = bk[j], aV = bv[j];
        for (int d = 0; d < DM; ++d) {
            float p = prow[d];
            aK += p * wk[d * DM + j];
            aV += p * wv[d * DM + j];
        }
        int h = j / HD, d = j % HD;
        kbf[(h * NP + r) * HD + d] = f2bf(aK * scale);
        vtbf[j * NP + r]           = f2bf(aV);
    }
}

// ---------------------------------------------------------------------------
// Fused pipeline, 4 rows (64 token-rows, 15 real + 1 pad each) per block.
// Every weight fragment load feeds 4 MFMAs (Mt=0..3).
// LDS: regA 96K (pe f32 -> q bf16 -> rep bf16) + pebf 16K + pbuf 36.9K
//      + srow/red ~4.7K  = ~152.6KB -> 1 block/CU, 8 waves.
// ---------------------------------------------------------------------------
__global__ __launch_bounds__(TPB, 2) void row_kernel(
    const float* __restrict__ state,
    const float* __restrict__ w_scalar, const float* __restrict__ b_scalar,
    const float* __restrict__ w_patch,  const float* __restrict__ b_patch,
    const float* __restrict__ feat_emb,
    const float* __restrict__ pn_g, const float* __restrict__ pn_b,
    const unsigned short* __restrict__ wqT, const float* __restrict__ bq,
    const unsigned short* __restrict__ wpT, const float* __restrict__ bp,
    const unsigned short* __restrict__ woT, const float* __restrict__ bo,
    const float* __restrict__ on_g, const float* __restrict__ on_b,
    const unsigned short* __restrict__ kbf, const unsigned short* __restrict__ vtbf,
    float* __restrict__ out, int Nrows)
{
    int tid  = threadIdx.x;
    int w    = tid >> 6, lane = tid & 63;
    int kg   = lane >> 4, lr = lane & 15;
    int nb   = blockIdx.x;

    __shared__ __align__(16) char regA[64 * 1536];          // 96KB, time-aliased
    __shared__ __align__(16) char pebf[64 * 256];           // 16KB
    __shared__ __align__(16) unsigned short pbuf[NH * 64 * PPAD]; // 36.9KB
    __shared__ float srow[RPB * 36];
    __shared__ float redS[8][64], redS2[8][64];

    float* peF = (float*)regA;   // [64][128] f32 view during build/LN

    // ---- load 4 state rows ----------------------------------------------
    if (tid < RPB * 36) {
        int rr = tid / 36;
        int gr = nb * RPB + rr;
        srow[tid] = (gr < Nrows) ? state[(size_t)gr * 36 + (tid - rr * 36)] : 0.f;
    }
    __syncthreads();

    // ---- build pe f32 (4 rows x 15 tokens x 128) into regA alias ---------
    for (int idx = tid; idx < RPB * NTOK * DP; idx += TPB) {
        int rr  = idx / (NTOK * DP);
        int rem = idx - rr * (NTOK * DP);
        int t = rem >> 7, d = rem & 127;
        const float* sr = &srow[rr * 36];
        float val;
        if (t == 0) {
            val = sr[5]  * w_scalar[0 * DP + d] + b_scalar[0 * DP + d] + feat_emb[0 * DP + d];
        } else if (t == 1) {
            val = sr[11] * w_scalar[1 * DP + d] + b_scalar[1 * DP + d] + feat_emb[1 * DP + d];
        } else if (t == 14) {
            val = sr[35] * w_scalar[2 * DP + d] + b_scalar[2 * DP + d] + feat_emb[5 * DP + d];
        } else {
            int f = (t - 2) / 4;
            int k = (t - 2) % 4;
            const float* pr = &sr[(2 + f) * 6];
            float acc = b_patch[f * DP + d] + feat_emb[(2 + f) * DP + d];
            for (int p = 0; p < 3; ++p) acc += pr[k + p] * w_patch[(f * 3 + p) * DP + d];
            val = acc;
        }
        peF[(rr * 16 + t) * DP + d] = val;
    }
    __syncthreads();

    // ---- LayerNorm(pe) + bf16 swizzled store: 8 lanes per token-row ------
    {
        int g = tid >> 3, ln = tid & 7;         // g = 0..63
        int t = g & 15;
        int gr = nb * RPB + (g >> 4);
        if (t == 15 || gr >= Nrows) {
            for (int d = ln; d < DP; d += 8)
                *(unsigned short*)(pebf + swzP(g, d * 2)) = 0;
        } else {
            float s = 0.f, s2 = 0.f;
            for (int d = ln; d < DP; d += 8) { float x = peF[g * DP + d]; s += x; s2 += x * x; }
            for (int off = 4; off; off >>= 1) {
                s  += __shfl_xor(s,  off, 64);
                s2 += __shfl_xor(s2, off, 64);
            }
            float m   = s / DP;
            float var = s2 / DP - m * m;
            float rin = 1.0f / sqrtf(var + EPSF);
            for (int d = ln; d < DP; d += 8) {
                float x = (peF[g * DP + d] - m) * rin * pn_g[d] + pn_b[d];
                *(unsigned short*)(pebf + swzP(g, d * 2)) = f2bf(x);
            }
        }
    }
    __syncthreads();   // peF dead; regA becomes q

    // ---- q = pe @ wq + bq via MFMA -> regA bf16 (M=64, wave cols=96) -----
    {
        int n0 = w * 96;
        bf16x8 ap[4][4];
        #pragma unroll
        for (int Mt = 0; Mt < 4; ++Mt)
            #pragma unroll
            for (int kk = 0; kk < 4; ++kk)
                ap[Mt][kk] = *(const bf16x8*)(pebf + swzP(Mt * 16 + lr, (kk * 32 + kg * 8) * 2));
        #pragma unroll
        for (int nt = 0; nt < 6; ++nt) {
            int col = n0 + nt * 16 + lr;
            f32x4 a[4];
            #pragma unroll
            for (int Mt = 0; Mt < 4; ++Mt) a[Mt] = (f32x4){0.f, 0.f, 0.f, 0.f};
            #pragma unroll
            for (int kk = 0; kk < 4; ++kk) {
                bf16x8 b = *(const bf16x8*)(wqT + col * DP + kk * 32 + kg * 8);
                #pragma unroll
                for (int Mt = 0; Mt < 4; ++Mt)
                    a[Mt] = __builtin_amdgcn_mfma_f32_16x16x32_bf16(ap[Mt][kk], b, a[Mt], 0, 0, 0);
            }
            float bqv = bq[col];
            #pragma unroll
            for (int Mt = 0; Mt < 4; ++Mt)
                #pragma unroll
                for (int r = 0; r < 4; ++r)
                    *(unsigned short*)(regA + swzA(Mt * 16 + kg * 4 + r, col * 2)) = f2bf(a[Mt][r] + bqv);
        }
    }
    __syncthreads();

    // ---- scores^T = K_scaled @ q^T (per head; wave = half of token-tiles)
    {
        int h = w >> 1, Nt0 = (w & 1) * 2;
        bf16x8 ka[4][6];
        #pragma unroll
        for (int Mt = 0; Mt < 4; ++Mt)
            #pragma unroll
            for (int kk = 0; kk < 6; ++kk)
                ka[Mt][kk] = *(const bf16x8*)(kbf + ((size_t)(h * NP + Mt * 16 + lr) * HD + kk * 32 + kg * 8));
        #pragma unroll
        for (int Ntl = 0; Ntl < 2; ++Ntl) {
            int Nt = Nt0 + Ntl;
            bf16x8 qB[6];
            #pragma unroll
            for (int kk = 0; kk < 6; ++kk)
                qB[kk] = *(const bf16x8*)(regA + swzA(Nt * 16 + lr, (h * HD + kk * 32 + kg * 8) * 2));
            f32x4 sacc[4];
            #pragma unroll
            for (int Mt = 0; Mt < 4; ++Mt) {
                f32x4 a = {0.f, 0.f, 0.f, 0.f};
                #pragma unroll
                for (int kk = 0; kk < 6; ++kk)
                    a = __builtin_amdgcn_mfma_f32_16x16x32_bf16(ka[Mt][kk], qB[kk], a, 0, 0, 0);
                sacc[Mt] = a;
            }
            // softmax over p for column token = Nt*16+lr
            float mx = -3.4e38f;
            #pragma unroll
            for (int Mt = 0; Mt < 4; ++Mt)
                #pragma unroll
                for (int r = 0; r < 4; ++r) mx = fmaxf(mx, sacc[Mt][r]);
            mx = fmaxf(mx, __shfl_xor(mx, 16, 64));
            mx = fmaxf(mx, __shfl_xor(mx, 32, 64));
            float sum = 0.f;
            f32x4 ee[4];
            #pragma unroll
            for (int Mt = 0; Mt < 4; ++Mt)
                #pragma unroll
                for (int r = 0; r < 4; ++r) { float e = __expf(sacc[Mt][r] - mx); ee[Mt][r] = e; sum += e; }
            sum += __shfl_xor(sum, 16, 64);
            sum += __shfl_xor(sum, 32, 64);
            float inv = 1.0f / sum;
            #pragma unroll
            for (int Mt = 0; Mt < 4; ++Mt)
                #pragma unroll
                for (int r = 0; r < 4; ++r)
                    pbuf[(h * 64 + Nt * 16 + lr) * PPAD + Mt * 16 + kg * 4 + r] = f2bf(ee[Mt][r] * inv);
        }
    }
    __syncthreads();   // pbuf ready; all q reads done -> regA becomes rep

    // ---- rep = P @ V (M=64 tok, wave d-cols = 96) ------------------------
    {
        int h = w >> 1;
        bf16x8 pa[4][2];
        #pragma unroll
        for (int Mt = 0; Mt < 4; ++Mt)
            #pragma unroll
            for (int kk = 0; kk < 2; ++kk)
                pa[Mt][kk] = *(const bf16x8*)((const char*)pbuf +
                              ((h * 64 + Mt * 16 + lr) * PPAD + kk * 32 + kg * 8) * 2);
        #pragma unroll
        for (int nt = 0; nt < 6; ++nt) {
            int dcol = w * 96 + nt * 16 + lr;   // == h*HD + (w&1)*96 + nt*16 + lr
            f32x4 a[4];
            #pragma unroll
            for (int Mt = 0; Mt < 4; ++Mt) a[Mt] = (f32x4){0.f, 0.f, 0.f, 0.f};
            #pragma unroll
            for (int kk = 0; kk < 2; ++kk) {
                bf16x8 b = *(const bf16x8*)(vtbf + (size_t)dcol * NP + kk * 32 + kg * 8);
                #pragma unroll
                for (int Mt = 0; Mt < 4; ++Mt)
                    a[Mt] = __builtin_amdgcn_mfma_f32_16x16x32_bf16(pa[Mt][kk], b, a[Mt], 0, 0, 0);
            }
            #pragma unroll
            for (int Mt = 0; Mt < 4; ++Mt)
                #pragma unroll
                for (int r = 0; r < 4; ++r)
                    *(unsigned short*)(regA + swzA(Mt * 16 + kg * 4 + r, dcol * 2)) = f2bf(a[Mt][r]);
        }
    }
    __syncthreads();

    // ---- out = LN(rep@wo + pe@wp + bo + bp), kkc-chunked A-cache ---------
    {
        int n0 = w * 96;
        f32x4 acc[6][4];
        #pragma unroll
        for (int nt = 0; nt < 6; ++nt) {
            int col = n0 + nt * 16 + lr;
            float bias = bo[col] + bp[col];
            #pragma unroll
            for (int Mt = 0; Mt < 4; ++Mt) acc[nt][Mt] = (f32x4){bias, bias, bias, bias};
        }
        #pragma unroll
        for (int kkc = 0; kkc < 4; ++kkc) {
            bf16x8 aw[4][6];
            #pragma unroll
            for (int Mt = 0; Mt < 4; ++Mt)
                #pragma unroll
                for (int kk = 0; kk < 6; ++kk)
                    aw[Mt][kk] = *(const bf16x8*)(regA + swzA(Mt * 16 + lr, (kkc * 192 + kk * 32 + kg * 8) * 2));
            #pragma unroll
            for (int nt = 0; nt < 6; ++nt) {
                int col = n0 + nt * 16 + lr;
                #pragma unroll
                for (int kk = 0; kk < 6; ++kk) {
                    bf16x8 b = *(const bf16x8*)(woT + (size_t)col * DM + kkc * 192 + kk * 32 + kg * 8);
                    #pragma unroll
                    for (int Mt = 0; Mt < 4; ++Mt)
                        acc[nt][Mt] = __builtin_amdgcn_mfma_f32_16x16x32_bf16(aw[Mt][kk], b, acc[nt][Mt], 0, 0, 0);
                }
            }
        }
        {
            bf16x8 apf[4][4];
            #pragma unroll
            for (int Mt = 0; Mt < 4; ++Mt)
                #pragma unroll
                for (int kk = 0; kk < 4; ++kk)
                    apf[Mt][kk] = *(const bf16x8*)(pebf + swzP(Mt * 16 + lr, (kk * 32 + kg * 8) * 2));
            #pragma unroll
            for (int nt = 0; nt < 6; ++nt) {
                int col = n0 + nt * 16 + lr;
                #pragma unroll
                for (int kk = 0; kk < 4; ++kk) {
                    bf16x8 b = *(const bf16x8*)(wpT + col * DP + kk * 32 + kg * 8);
                    #pragma unroll
                    for (int Mt = 0; Mt < 4; ++Mt)
                        acc[nt][Mt] = __builtin_amdgcn_mfma_f32_16x16x32_bf16(apf[Mt][kk], b, acc[nt][Mt], 0, 0, 0);
                }
            }
        }

        // LN stats: reduce over lr lanes, combine across waves in LDS
        float sS[4][4], sQ[4][4];
        #pragma unroll
        for (int Mt = 0; Mt < 4; ++Mt)
            #pragma unroll
            for (int r = 0; r < 4; ++r) {
                float s = 0.f, q = 0.f;
                #pragma unroll
                for (int nt = 0; nt < 6; ++nt) { float v = acc[nt][Mt][r]; s += v; q += v * v; }
                #pragma unroll
                for (int off = 8; off; off >>= 1) {
                    s += __shfl_xor(s, off, 64);
                    q += __shfl_xor(q, off, 64);
                }
                sS[Mt][r] = s; sQ[Mt][r] = q;
            }
        if (lr == 0) {
            #pragma unroll
            for (int Mt = 0; Mt < 4; ++Mt)
                #pragma unroll
                for (int r = 0; r < 4; ++r) {
                    int tok = Mt * 16 + kg * 4 + r;
                    redS [w][tok] = sS[Mt][r];
                    redS2[w][tok] = sQ[Mt][r];
                }
        }
        __syncthreads();
        float mA[4][4], riA[4][4];
        #pragma unroll
        for (int Mt = 0; Mt < 4; ++Mt)
            #pragma unroll
            for (int r = 0; r < 4; ++r) {
                int tok = Mt * 16 + kg * 4 + r;
                float ts = 0.f, tq = 0.f;
                #pragma unroll
                for (int ww = 0; ww < 8; ++ww) { ts += redS[ww][tok]; tq += redS2[ww][tok]; }
                float mm  = ts / DM;
                float var = tq / DM - mm * mm;
                mA[Mt][r]  = mm;
                riA[Mt][r] = 1.0f / sqrtf(var + EPSF);
            }
        #pragma unroll
        for (int nt = 0; nt < 6; ++nt) {
            int col = n0 + nt * 16 + lr;
            float g = on_g[col], bb = on_b[col];
            #pragma unroll
            for (int Mt = 0; Mt < 4; ++Mt)
                #pragma unroll
                for (int r = 0; r < 4; ++r) {
                    int tok = Mt * 16 + kg * 4 + r;
                    int t = tok & 15, rr = tok >> 4;
                    int gr = nb * RPB + rr;
                    if (t < NTOK && gr < Nrows)
                        out[((size_t)gr * NTOK + t) * DM + col] =
                            (acc[nt][Mt][r] - mA[Mt][r]) * riA[Mt][r] * g + bb;
                }
        }
    }
}

extern "C" void kernel_launch(void* const* d_in, const int* in_sizes, int n_in,
                              void* d_out, int out_size, void* d_ws, size_t ws_size,
                              hipStream_t stream) {
    const float* state    = (const float*)d_in[0];
    const float* w_scalar = (const float*)d_in[1];
    const float* b_scalar = (const float*)d_in[2];
    const float* w_patch  = (const float*)d_in[3];
    const float* b_patch  = (const float*)d_in[4];
    const float* feat_emb = (const float*)d_in[5];
    const float* pn_g     = (const float*)d_in[6];
    const float* pn_b     = (const float*)d_in[7];
    const float* wq       = (const float*)d_in[8];
    const float* bq       = (const float*)d_in[9];
    const float* wk       = (const float*)d_in[10];
    const float* bk       = (const float*)d_in[11];
    const float* wv       = (const float*)d_in[12];
    const float* bv       = (const float*)d_in[13];
    const float* wp       = (const float*)d_in[14];
    const float* bp       = (const float*)d_in[15];
    const float* wo       = (const float*)d_in[16];
    const float* bo       = (const float*)d_in[17];
    const float* on_g     = (const float*)d_in[18];
    const float* on_b     = (const float*)d_in[19];
    const float* protos   = (const float*)d_in[20];
    float* out = (float*)d_out;

    unsigned short* kbf  = (unsigned short*)d_ws;   // [4][64][192] bf16, pre-scaled
    unsigned short* vtbf = kbf + DM * NP;           // [768][64] bf16
    unsigned short* wqT  = vtbf + DM * NP;          // [768][128] bf16
    unsigned short* woT  = wqT + DM * DP;           // [768][768] bf16
    unsigned short* wpT  = woT + DM * DM;           // [768][128] bf16

    int N = in_sizes[0] / 36;
    int nblk = (N + RPB - 1) / RPB;

    hipLaunchKernelGGL(wT_bf16_kernel, dim3((DP * DM + 255) / 256), dim3(256), 0, stream, wq, wqT, DP, DM);
    hipLaunchKernelGGL(wT_bf16_kernel, dim3((DM * DM + 255) / 256), dim3(256), 0, stream, wo, woT, DM, DM);
    hipLaunchKernelGGL(wT_bf16_kernel, dim3((DP * DM + 255) / 256), dim3(256), 0, stream, wp, wpT, DP, DM);
    hipLaunchKernelGGL(kv_kernel, dim3(NP), dim3(256), 0, stream,
                       protos, wk, bk, wv, bv, kbf, vtbf);
    hipLaunchKernelGGL(row_kernel, dim3(nblk), dim3(TPB), 0, stream,
                       state, w_scalar, b_scalar, w_patch, b_patch, feat_emb,
                       pn_g, pn_b, wqT, bq, wpT, bp, woT, bo, on_g, on_b,
                       kbf, vtbf, out, N);
}

// Round 9
// 349.640 us; speedup vs baseline: 19.1336x; 1.3952x over previous
//
#include <hip/hip_runtime.h>

#define NTOK 15
#define DP   128
#define DM   768
#define NH   4
#define HD   192
#define NP   64
#define EPSF 1e-5f
#define RPB  4      // rows per block
#define TPB  512    // 8 waves

typedef __attribute__((ext_vector_type(8))) short bf16x8;   // 8 bf16 = 4 VGPR
typedef __attribute__((ext_vector_type(4))) float f32x4;

__device__ __forceinline__ unsigned short f2bf(float x) {
    unsigned u = __float_as_uint(x);
    u = (u + 0x7FFF + ((u >> 16) & 1)) >> 16;   // RNE
    return (unsigned short)u;
}
// swizzled LDS byte addresses (row strides 256B / 512B)
__device__ __forceinline__ int swzP(int row, int b) { return row * 256 + (b ^ ((row & 7) << 4)); }
__device__ __forceinline__ int swzB(int row, int b) { return row * 512 + (b ^ ((row & 7) << 4)); }

// ---------------------------------------------------------------------------
// Prep: dst[N][K] bf16 = transpose(src[K][N] f32)   (only wp now)
// ---------------------------------------------------------------------------
__global__ __launch_bounds__(256) void wT_bf16_kernel(
    const float* __restrict__ src, unsigned short* __restrict__ dst, int K, int N)
{
    int idx = blockIdx.x * 256 + threadIdx.x;
    if (idx >= K * N) return;
    int n = idx / K, k = idx - n * K;
    dst[idx] = f2bf(src[k * N + n]);
}

// ---------------------------------------------------------------------------
// Kraw[hp][192] f32 and Vf[p][768] f32 from protos.
// ---------------------------------------------------------------------------
__global__ __launch_bounds__(256) void kv_kernel(
    const float* __restrict__ protos,
    const float* __restrict__ wk, const float* __restrict__ bk,
    const float* __restrict__ wv, const float* __restrict__ bv,
    float* __restrict__ Kraw, float* __restrict__ Vf)
{
    int r = blockIdx.x;            // proto 0..63
    int tid = threadIdx.x;
    __shared__ float prow[DM];
    for (int i = tid; i < DM; i += 256) prow[i] = protos[r * DM + i];
    __syncthreads();
    for (int j = tid; j < DM; j += 256) {
        float aK = bk[j], aV = bv[j];
        for (int d = 0; d < DM; ++d) {
            float p = prow[d];
            aK += p * wk[d * DM + j];
            aV += p * wv[d * DM + j];
        }
        int h = j / HD, jj = j - h * HD;
        Kraw[(h * NP + r) * HD + jj] = aK;
        Vf[r * DM + j] = aV;
    }
}

// ---------------------------------------------------------------------------
// Fold K/V into weights:
//   KWb[hp][d]  = bf16( scale * sum_l wq[d][h*192+l] * Kraw[hp][l] )
//   kqb[hp]     = scale * sum_l bq[h*192+l] * Kraw[hp][l]
//   VWOT[j][hp] = bf16( sum_l Vf[p][h*192+l] * wo[h*192+l][j] )
// One block per hp (h*64+p).
// ---------------------------------------------------------------------------
__global__ __launch_bounds__(256) void kwvwo_kernel(
    const float* __restrict__ Kraw, const float* __restrict__ Vf,
    const float* __restrict__ wq, const float* __restrict__ bq,
    const float* __restrict__ wo,
    unsigned short* __restrict__ KWb, float* __restrict__ kqb,
    unsigned short* __restrict__ VWOT)
{
    int hp = blockIdx.x, h = hp >> 6, p = hp & 63;
    int tid = threadIdx.x;
    __shared__ float Kl[HD], Vl[HD];
    if (tid < HD) {
        Kl[tid] = Kraw[hp * HD + tid];
        Vl[tid] = Vf[p * DM + h * HD + tid];
    }
    __syncthreads();
    const float scale = 0.07216878364870323f;   // 1/sqrt(192)
    if (tid < DP) {
        float a = 0.f;
        for (int l = 0; l < HD; ++l) a += wq[tid * DM + h * HD + l] * Kl[l];
        KWb[hp * DP + tid] = f2bf(scale * a);
    } else if (tid == DP) {
        float a = 0.f;
        for (int l = 0; l < HD; ++l) a += bq[h * HD + l] * Kl[l];
        kqb[hp] = scale * a;
    }
    for (int jj = 0; jj < 3; ++jj) {
        int j = jj * 256 + tid;
        float a = 0.f;
        for (int l = 0; l < HD; ++l) a += wo[(h * HD + l) * DM + j] * Vl[l];
        VWOT[(size_t)j * 256 + hp] = f2bf(a);
    }
}

// ---------------------------------------------------------------------------
// Fused per-row pipeline with folded weights.
// scores = pe @ KW^T + kqb ; attn -> abuf[64tok][256] ; out = LN(attn@VWO + pe@wp + b)
// LDS: bufA 32K (peF f32 -> abuf bf16) + pebf 16K + srow + red 4.6K ~ 54KB.
// launch_bounds(512,4) -> VGPR<=128 -> 2 blocks/CU, 16 waves/CU.
// ---------------------------------------------------------------------------
__global__ __launch_bounds__(TPB, 4) void row_kernel(
    const float* __restrict__ state,
    const float* __restrict__ w_scalar, const float* __restrict__ b_scalar,
    const float* __restrict__ w_patch,  const float* __restrict__ b_patch,
    const float* __restrict__ feat_emb,
    const float* __restrict__ pn_g, const float* __restrict__ pn_b,
    const unsigned short* __restrict__ KWb, const float* __restrict__ kqb,
    const unsigned short* __restrict__ VWOT,
    const unsigned short* __restrict__ wpT, const float* __restrict__ bp,
    const float* __restrict__ bo,
    const float* __restrict__ on_g, const float* __restrict__ on_b,
    float* __restrict__ out, int Nrows)
{
    int tid = threadIdx.x;
    int w = tid >> 6, lane = tid & 63;
    int kg = lane >> 4, lr = lane & 15;
    int nb = blockIdx.x;

    __shared__ __align__(16) char bufA[64 * 512];   // peF f32 [64][128] -> abuf bf16
    __shared__ __align__(16) char pebf[64 * 256];
    __shared__ float srow[RPB * 36];
    __shared__ float redS[8][64], redS2[8][64];

    float* peF = (float*)bufA;

    // ---- load 4 state rows ----------------------------------------------
    if (tid < RPB * 36) {
        int rr = tid / 36;
        int gr = nb * RPB + rr;
        srow[tid] = (gr < Nrows) ? state[(size_t)gr * 36 + (tid - rr * 36)] : 0.f;
    }
    __syncthreads();

    // ---- build pe f32 ----------------------------------------------------
    for (int idx = tid; idx < RPB * NTOK * DP; idx += TPB) {
        int rr  = idx / (NTOK * DP);
        int rem = idx - rr * (NTOK * DP);
        int t = rem >> 7, d = rem & 127;
        const float* sr = &srow[rr * 36];
        float val;
        if (t == 0) {
            val = sr[5]  * w_scalar[0 * DP + d] + b_scalar[0 * DP + d] + feat_emb[0 * DP + d];
        } else if (t == 1) {
            val = sr[11] * w_scalar[1 * DP + d] + b_scalar[1 * DP + d] + feat_emb[1 * DP + d];
        } else if (t == 14) {
            val = sr[35] * w_scalar[2 * DP + d] + b_scalar[2 * DP + d] + feat_emb[5 * DP + d];
        } else {
            int f = (t - 2) / 4;
            int k = (t - 2) % 4;
            const float* pr = &sr[(2 + f) * 6];
            float acc = b_patch[f * DP + d] + feat_emb[(2 + f) * DP + d];
            for (int p = 0; p < 3; ++p) acc += pr[k + p] * w_patch[(f * 3 + p) * DP + d];
            val = acc;
        }
        peF[(rr * 16 + t) * DP + d] = val;
    }
    __syncthreads();

    // ---- LayerNorm(pe) -> pebf bf16 swizzled (8 lanes per token-row) -----
    {
        int g = tid >> 3, ln = tid & 7;
        int t = g & 15;
        int gr = nb * RPB + (g >> 4);
        if (t == 15 || gr >= Nrows) {
            for (int d = ln; d < DP; d += 8)
                *(unsigned short*)(pebf + swzP(g, d * 2)) = 0;
        } else {
            float s = 0.f, s2 = 0.f;
            for (int d = ln; d < DP; d += 8) { float x = peF[g * DP + d]; s += x; s2 += x * x; }
            for (int off = 4; off; off >>= 1) {
                s  += __shfl_xor(s,  off, 64);
                s2 += __shfl_xor(s2, off, 64);
            }
            float m   = s / DP;
            float var = s2 / DP - m * m;
            float rin = 1.0f / sqrtf(var + EPSF);
            for (int d = ln; d < DP; d += 8) {
                float x = (peF[g * DP + d] - m) * rin * pn_g[d] + pn_b[d];
                *(unsigned short*)(pebf + swzP(g, d * 2)) = f2bf(x);
            }
        }
    }
    __syncthreads();   // peF dead; bufA becomes abuf

    // ---- scores^T = KW @ pe^T + kqb; softmax over p; attn -> abuf --------
    {
        int h = w >> 1, Nt0 = (w & 1) * 2;
        const unsigned short* kwh = KWb + (size_t)h * NP * DP;
        bf16x8 ka[4][4];
        #pragma unroll
        for (int Mt = 0; Mt < 4; ++Mt)
            #pragma unroll
            for (int kk = 0; kk < 4; ++kk)
                ka[Mt][kk] = *(const bf16x8*)(kwh + (Mt * 16 + lr) * DP + kk * 32 + kg * 8);
        #pragma unroll
        for (int Ntl = 0; Ntl < 2; ++Ntl) {
            int Nt = Nt0 + Ntl;
            bf16x8 qb[4];
            #pragma unroll
            for (int kk = 0; kk < 4; ++kk)
                qb[kk] = *(const bf16x8*)(pebf + swzP(Nt * 16 + lr, (kk * 32 + kg * 8) * 2));
            f32x4 sacc[4];
            #pragma unroll
            for (int Mt = 0; Mt < 4; ++Mt) sacc[Mt] = (f32x4){0.f, 0.f, 0.f, 0.f};
            #pragma unroll
            for (int kk = 0; kk < 4; ++kk)
                #pragma unroll
                for (int Mt = 0; Mt < 4; ++Mt)
                    sacc[Mt] = __builtin_amdgcn_mfma_f32_16x16x32_bf16(ka[Mt][kk], qb[kk], sacc[Mt], 0, 0, 0);
            #pragma unroll
            for (int Mt = 0; Mt < 4; ++Mt) {
                float4 kq = *(const float4*)(kqb + h * 64 + Mt * 16 + kg * 4);
                sacc[Mt][0] += kq.x; sacc[Mt][1] += kq.y;
                sacc[Mt][2] += kq.z; sacc[Mt][3] += kq.w;
            }
            float mx = -3.4e38f;
            #pragma unroll
            for (int Mt = 0; Mt < 4; ++Mt)
                #pragma unroll
                for (int r = 0; r < 4; ++r) mx = fmaxf(mx, sacc[Mt][r]);
            mx = fmaxf(mx, __shfl_xor(mx, 16, 64));
            mx = fmaxf(mx, __shfl_xor(mx, 32, 64));
            float sum = 0.f;
            f32x4 ee[4];
            #pragma unroll
            for (int Mt = 0; Mt < 4; ++Mt)
                #pragma unroll
                for (int r = 0; r < 4; ++r) { float e = __expf(sacc[Mt][r] - mx); ee[Mt][r] = e; sum += e; }
            sum += __shfl_xor(sum, 16, 64);
            sum += __shfl_xor(sum, 32, 64);
            float inv = 1.0f / sum;
            #pragma unroll
            for (int Mt = 0; Mt < 4; ++Mt)
                #pragma unroll
                for (int r = 0; r < 4; ++r) {
                    int c = h * 64 + Mt * 16 + kg * 4 + r;
                    *(unsigned short*)(bufA + swzB(Nt * 16 + lr, c * 2)) = f2bf(ee[Mt][r] * inv);
                }
        }
    }
    __syncthreads();

    // ---- out = LN(attn@VWO + pe@wp + bo + bp), two token-halves ----------
    const int n0 = w * 96;
    #pragma unroll
    for (int half = 0; half < 2; ++half) {
        f32x4 acc[6][2];
        #pragma unroll
        for (int nt = 0; nt < 6; ++nt) {
            int col = n0 + nt * 16 + lr;
            float bias = bo[col] + bp[col];
            #pragma unroll
            for (int Mtl = 0; Mtl < 2; ++Mtl) acc[nt][Mtl] = (f32x4){bias, bias, bias, bias};
        }
        #pragma unroll
        for (int kkc = 0; kkc < 2; ++kkc) {
            bf16x8 aw[2][4];
            #pragma unroll
            for (int Mtl = 0; Mtl < 2; ++Mtl)
                #pragma unroll
                for (int kk = 0; kk < 4; ++kk)
                    aw[Mtl][kk] = *(const bf16x8*)(bufA +
                        swzB((half * 2 + Mtl) * 16 + lr, (kkc * 128 + kk * 32 + kg * 8) * 2));
            #pragma unroll
            for (int nt = 0; nt < 6; ++nt) {
                int col = n0 + nt * 16 + lr;
                #pragma unroll
                for (int kk = 0; kk < 4; ++kk) {
                    bf16x8 b = *(const bf16x8*)(VWOT + (size_t)col * 256 + kkc * 128 + kk * 32 + kg * 8);
                    #pragma unroll
                    for (int Mtl = 0; Mtl < 2; ++Mtl)
                        acc[nt][Mtl] = __builtin_amdgcn_mfma_f32_16x16x32_bf16(aw[Mtl][kk], b, acc[nt][Mtl], 0, 0, 0);
                }
            }
        }
        {
            bf16x8 apf[2][4];
            #pragma unroll
            for (int Mtl = 0; Mtl < 2; ++Mtl)
                #pragma unroll
                for (int kk = 0; kk < 4; ++kk)
                    apf[Mtl][kk] = *(const bf16x8*)(pebf +
                        swzP((half * 2 + Mtl) * 16 + lr, (kk * 32 + kg * 8) * 2));
            #pragma unroll
            for (int nt = 0; nt < 6; ++nt) {
                int col = n0 + nt * 16 + lr;
                #pragma unroll
                for (int kk = 0; kk < 4; ++kk) {
                    bf16x8 b = *(const bf16x8*)(wpT + col * DP + kk * 32 + kg * 8);
                    #pragma unroll
                    for (int Mtl = 0; Mtl < 2; ++Mtl)
                        acc[nt][Mtl] = __builtin_amdgcn_mfma_f32_16x16x32_bf16(apf[Mtl][kk], b, acc[nt][Mtl], 0, 0, 0);
                }
            }
        }
        // LN stats: per-lane over nt, reduce over 16 lr lanes, cross-wave LDS
        #pragma unroll
        for (int Mtl = 0; Mtl < 2; ++Mtl)
            #pragma unroll
            for (int r = 0; r < 4; ++r) {
                float s = 0.f, q = 0.f;
                #pragma unroll
                for (int nt = 0; nt < 6; ++nt) { float v = acc[nt][Mtl][r]; s += v; q += v * v; }
                #pragma unroll
                for (int off = 8; off; off >>= 1) {
                    s += __shfl_xor(s, off, 64);
                    q += __shfl_xor(q, off, 64);
                }
                if (lr == 0) {
                    int tok = (half * 2 + Mtl) * 16 + kg * 4 + r;
                    redS [w][tok] = s;
                    redS2[w][tok] = q;
                }
            }
        __syncthreads();
        #pragma unroll
        for (int Mtl = 0; Mtl < 2; ++Mtl) {
            float mA[4], riA[4];
            #pragma unroll
            for (int r = 0; r < 4; ++r) {
                int tok = (half * 2 + Mtl) * 16 + kg * 4 + r;
                float ts = 0.f, tq = 0.f;
                #pragma unroll
                for (int ww = 0; ww < 8; ++ww) { ts += redS[ww][tok]; tq += redS2[ww][tok]; }
                float mm  = ts / DM;
                float var = tq / DM - mm * mm;
                mA[r]  = mm;
                riA[r] = 1.0f / sqrtf(var + EPSF);
            }
            #pragma unroll
            for (int nt = 0; nt < 6; ++nt) {
                int col = n0 + nt * 16 + lr;
                float g = on_g[col], bb = on_b[col];
                #pragma unroll
                for (int r = 0; r < 4; ++r) {
                    int tok = (half * 2 + Mtl) * 16 + kg * 4 + r;
                    int t = tok & 15, rr = tok >> 4;
                    int gr = nb * RPB + rr;
                    if (t < NTOK && gr < Nrows)
                        out[((size_t)gr * NTOK + t) * DM + col] =
                            (acc[nt][Mtl][r] - mA[r]) * riA[r] * g + bb;
                }
            }
        }
    }
}

extern "C" void kernel_launch(void* const* d_in, const int* in_sizes, int n_in,
                              void* d_out, int out_size, void* d_ws, size_t ws_size,
                              hipStream_t stream) {
    const float* state    = (const float*)d_in[0];
    const float* w_scalar = (const float*)d_in[1];
    const float* b_scalar = (const float*)d_in[2];
    const float* w_patch  = (const float*)d_in[3];
    const float* b_patch  = (const float*)d_in[4];
    const float* feat_emb = (const float*)d_in[5];
    const float* pn_g     = (const float*)d_in[6];
    const float* pn_b     = (const float*)d_in[7];
    const float* wq       = (const float*)d_in[8];
    const float* bq       = (const float*)d_in[9];
    const float* wk       = (const float*)d_in[10];
    const float* bk       = (const float*)d_in[11];
    const float* wv       = (const float*)d_in[12];
    const float* bv       = (const float*)d_in[13];
    const float* wp       = (const float*)d_in[14];
    const float* bp       = (const float*)d_in[15];
    const float* wo       = (const float*)d_in[16];
    const float* bo       = (const float*)d_in[17];
    const float* on_g     = (const float*)d_in[18];
    const float* on_b     = (const float*)d_in[19];
    const float* protos   = (const float*)d_in[20];
    float* out = (float*)d_out;

    float*          Kraw = (float*)d_ws;            // 256*192 f32
    float*          Vf   = Kraw + 256 * HD;         // 64*768  f32
    float*          kqbp = Vf + NP * DM;            // 256     f32
    unsigned short* KWb  = (unsigned short*)(kqbp + 256);   // [256][128] bf16
    unsigned short* VWOT = KWb + 256 * DP;                  // [768][256] bf16
    unsigned short* wpT  = VWOT + (size_t)DM * 256;         // [768][128] bf16

    int N = in_sizes[0] / 36;
    int nblk = (N + RPB - 1) / RPB;

    hipLaunchKernelGGL(wT_bf16_kernel, dim3((DP * DM + 255) / 256), dim3(256), 0, stream, wp, wpT, DP, DM);
    hipLaunchKernelGGL(kv_kernel, dim3(NP), dim3(256), 0, stream,
                       protos, wk, bk, wv, bv, Kraw, Vf);
    hipLaunchKernelGGL(kwvwo_kernel, dim3(256), dim3(256), 0, stream,
                       Kraw, Vf, wq, bq, wo, KWb, kqbp, VWOT);
    hipLaunchKernelGGL(row_kernel, dim3(nblk), dim3(TPB), 0, stream,
                       state, w_scalar, b_scalar, w_patch, b_patch, feat_emb,
                       pn_g, pn_b, KWb, kqbp, VWOT, wpT, bp, bo, on_g, on_b,
                       out, N);
}

// Round 10
// 310.163 us; speedup vs baseline: 21.5689x; 1.1273x over previous
//
#include <hip/hip_runtime.h>

#define NTOK 15
#define DP   128
#define DM   768
#define NH   4
#define HD   192
#define NP   64
#define EPSF 1e-5f
#define RPB  4      // rows per block
#define TPB  512    // 8 waves
#define KW   384    // Wcat K-width (256 VWO + 128 wp)

typedef __attribute__((ext_vector_type(8))) short bf16x8;   // 8 bf16 = 4 VGPR
typedef __attribute__((ext_vector_type(4))) float f32x4;

__device__ __forceinline__ unsigned short f2bf(float x) {
    unsigned u = __float_as_uint(x);
    u = (u + 0x7FFF + ((u >> 16) & 1)) >> 16;   // RNE
    return (unsigned short)u;
}
// swizzled LDS byte addresses (row strides 256B / 512B)
__device__ __forceinline__ int swzP(int row, int b) { return row * 256 + (b ^ ((row & 7) << 4)); }
__device__ __forceinline__ int swzB(int row, int b) { return row * 512 + (b ^ ((row & 7) << 4)); }

// ---------------------------------------------------------------------------
// P1: Kraw[hp][192] f32 and Vf[p][768] f32 from protos. 64 blocks x 768 thr.
// ---------------------------------------------------------------------------
__global__ __launch_bounds__(768) void kv_kernel(
    const float* __restrict__ protos,
    const float* __restrict__ wk, const float* __restrict__ bk,
    const float* __restrict__ wv, const float* __restrict__ bv,
    float* __restrict__ Kraw, float* __restrict__ Vf)
{
    int r = blockIdx.x;            // proto 0..63
    int j = threadIdx.x;           // col 0..767
    __shared__ float prow[DM];
    prow[j] = protos[r * DM + j];
    __syncthreads();
    float aK = bk[j], aV = bv[j];
    for (int d = 0; d < DM; ++d) {
        float p = prow[d];
        aK += p * wk[d * DM + j];
        aV += p * wv[d * DM + j];
    }
    int h = j / HD, jj = j - h * HD;
    Kraw[(h * NP + r) * HD + jj] = aK;
    Vf[r * DM + j] = aV;
}

// ---------------------------------------------------------------------------
// P2: fold K/V into weights + build Wcat.
//  blocks 0..255   (hp): KWb[hp][d] = bf16(scale * wq[d,:h] . Kraw[hp])
//                        kqb[hp]    = scale * bq[:h] . Kraw[hp]
//                        Wcat[j][hp]= bf16(Vf[p][:h] . wo[:h][j])   j=0..767
//  blocks 256..639      : Wcat[j][256+d] = bf16(wp[d][j])
// ---------------------------------------------------------------------------
__global__ __launch_bounds__(256) void fold_kernel(
    const float* __restrict__ Kraw, const float* __restrict__ Vf,
    const float* __restrict__ wq, const float* __restrict__ bq,
    const float* __restrict__ wo, const float* __restrict__ wp,
    unsigned short* __restrict__ KWb, float* __restrict__ kqb,
    unsigned short* __restrict__ Wcat)
{
    int b = blockIdx.x, tid = threadIdx.x;
    if (b >= 256) {
        int idx = (b - 256) * 256 + tid;       // 0 .. 98303
        int j = idx >> 7, d = idx & 127;
        Wcat[(size_t)j * KW + 256 + d] = f2bf(wp[d * DM + j]);
        return;
    }
    int hp = b, h = hp >> 6, p = hp & 63;
    __shared__ float Kl[HD], Vl[HD];
    if (tid < HD) {
        Kl[tid] = Kraw[hp * HD + tid];
        Vl[tid] = Vf[p * DM + h * HD + tid];
    }
    __syncthreads();
    const float scale = 0.07216878364870323f;   // 1/sqrt(192)
    if (tid < DP) {
        float a = 0.f;
        for (int l = 0; l < HD; ++l) a += wq[tid * DM + h * HD + l] * Kl[l];
        KWb[hp * DP + tid] = f2bf(scale * a);
    } else if (tid == DP) {
        float a = 0.f;
        for (int l = 0; l < HD; ++l) a += bq[h * HD + l] * Kl[l];
        kqb[hp] = scale * a;
    }
    for (int jj = 0; jj < 3; ++jj) {
        int j = jj * 256 + tid;
        float a = 0.f;
        for (int l = 0; l < HD; ++l) a += wo[(h * HD + l) * DM + j] * Vl[l];
        Wcat[(size_t)j * KW + hp] = f2bf(a);
    }
}

// ---------------------------------------------------------------------------
// Fused per-row pipeline with folded weights + pipelined out-GEMM.
// LDS: bufA 32K (peF f32 -> abuf bf16) + pebf 16K + srow + red ~ 54KB.
// launch_bounds(512,4) -> VGPR<=128 -> 2 blocks/CU, 16 waves/CU.
// ---------------------------------------------------------------------------
__global__ __launch_bounds__(TPB, 4) void row_kernel(
    const float* __restrict__ state,
    const float* __restrict__ w_scalar, const float* __restrict__ b_scalar,
    const float* __restrict__ w_patch,  const float* __restrict__ b_patch,
    const float* __restrict__ feat_emb,
    const float* __restrict__ pn_g, const float* __restrict__ pn_b,
    const unsigned short* __restrict__ KWb, const float* __restrict__ kqb,
    const unsigned short* __restrict__ Wcat,
    const float* __restrict__ bp, const float* __restrict__ bo,
    const float* __restrict__ on_g, const float* __restrict__ on_b,
    float* __restrict__ out, int Nrows)
{
    int tid = threadIdx.x;
    int w = tid >> 6, lane = tid & 63;
    int kg = lane >> 4, lr = lane & 15;
    int nb = blockIdx.x;

    __shared__ __align__(16) char bufA[64 * 512];   // peF f32 [64][128] -> abuf bf16
    __shared__ __align__(16) char pebf[64 * 256];
    __shared__ float srow[RPB * 36];
    __shared__ float redS[8][64], redS2[8][64];

    float* peF = (float*)bufA;

    // ---- load 4 state rows ----------------------------------------------
    if (tid < RPB * 36) {
        int rr = tid / 36;
        int gr = nb * RPB + rr;
        srow[tid] = (gr < Nrows) ? state[(size_t)gr * 36 + (tid - rr * 36)] : 0.f;
    }
    __syncthreads();

    // ---- build pe f32 ----------------------------------------------------
    for (int idx = tid; idx < RPB * NTOK * DP; idx += TPB) {
        int rr  = idx / (NTOK * DP);
        int rem = idx - rr * (NTOK * DP);
        int t = rem >> 7, d = rem & 127;
        const float* sr = &srow[rr * 36];
        float val;
        if (t == 0) {
            val = sr[5]  * w_scalar[0 * DP + d] + b_scalar[0 * DP + d] + feat_emb[0 * DP + d];
        } else if (t == 1) {
            val = sr[11] * w_scalar[1 * DP + d] + b_scalar[1 * DP + d] + feat_emb[1 * DP + d];
        } else if (t == 14) {
            val = sr[35] * w_scalar[2 * DP + d] + b_scalar[2 * DP + d] + feat_emb[5 * DP + d];
        } else {
            int f = (t - 2) / 4;
            int k = (t - 2) % 4;
            const float* pr = &sr[(2 + f) * 6];
            float acc = b_patch[f * DP + d] + feat_emb[(2 + f) * DP + d];
            for (int p = 0; p < 3; ++p) acc += pr[k + p] * w_patch[(f * 3 + p) * DP + d];
            val = acc;
        }
        peF[(rr * 16 + t) * DP + d] = val;
    }
    __syncthreads();

    // ---- HOISTED score-phase loads (no LDS dependency; hide under LN) ----
    const int h = w >> 1;
    bf16x8 ka[4][4];
    float4 kqv[4];
    {
        const unsigned short* kwh = KWb + (size_t)h * NP * DP;
        #pragma unroll
        for (int Mt = 0; Mt < 4; ++Mt) {
            #pragma unroll
            for (int kk = 0; kk < 4; ++kk)
                ka[Mt][kk] = *(const bf16x8*)(kwh + (Mt * 16 + lr) * DP + kk * 32 + kg * 8);
            kqv[Mt] = *(const float4*)(kqb + h * 64 + Mt * 16 + kg * 4);
        }
    }

    // ---- LayerNorm(pe) -> pebf bf16 swizzled (8 lanes per token-row) -----
    {
        int g = tid >> 3, ln = tid & 7;
        int t = g & 15;
        int gr = nb * RPB + (g >> 4);
        if (t == 15 || gr >= Nrows) {
            for (int d = ln; d < DP; d += 8)
                *(unsigned short*)(pebf + swzP(g, d * 2)) = 0;
        } else {
            float s = 0.f, s2 = 0.f;
            for (int d = ln; d < DP; d += 8) { float x = peF[g * DP + d]; s += x; s2 += x * x; }
            for (int off = 4; off; off >>= 1) {
                s  += __shfl_xor(s,  off, 64);
                s2 += __shfl_xor(s2, off, 64);
            }
            float m   = s / DP;
            float var = s2 / DP - m * m;
            float rin = 1.0f / sqrtf(var + EPSF);
            for (int d = ln; d < DP; d += 8) {
                float x = (peF[g * DP + d] - m) * rin * pn_g[d] + pn_b[d];
                *(unsigned short*)(pebf + swzP(g, d * 2)) = f2bf(x);
            }
        }
    }
    __syncthreads();   // peF dead; bufA becomes abuf

    // ---- scores^T = KW @ pe^T + kqb; softmax over p; attn -> abuf --------
    {
        int Nt0 = (w & 1) * 2;
        #pragma unroll
        for (int Ntl = 0; Ntl < 2; ++Ntl) {
            int Nt = Nt0 + Ntl;
            bf16x8 qb[4];
            #pragma unroll
            for (int kk = 0; kk < 4; ++kk)
                qb[kk] = *(const bf16x8*)(pebf + swzP(Nt * 16 + lr, (kk * 32 + kg * 8) * 2));
            f32x4 sacc[4];
            #pragma unroll
            for (int Mt = 0; Mt < 4; ++Mt) sacc[Mt] = (f32x4){0.f, 0.f, 0.f, 0.f};
            #pragma unroll
            for (int kk = 0; kk < 4; ++kk)
                #pragma unroll
                for (int Mt = 0; Mt < 4; ++Mt)
                    sacc[Mt] = __builtin_amdgcn_mfma_f32_16x16x32_bf16(ka[Mt][kk], qb[kk], sacc[Mt], 0, 0, 0);
            #pragma unroll
            for (int Mt = 0; Mt < 4; ++Mt) {
                sacc[Mt][0] += kqv[Mt].x; sacc[Mt][1] += kqv[Mt].y;
                sacc[Mt][2] += kqv[Mt].z; sacc[Mt][3] += kqv[Mt].w;
            }
            float mx = -3.4e38f;
            #pragma unroll
            for (int Mt = 0; Mt < 4; ++Mt)
                #pragma unroll
                for (int r = 0; r < 4; ++r) mx = fmaxf(mx, sacc[Mt][r]);
            mx = fmaxf(mx, __shfl_xor(mx, 16, 64));
            mx = fmaxf(mx, __shfl_xor(mx, 32, 64));
            float sum = 0.f;
            f32x4 ee[4];
            #pragma unroll
            for (int Mt = 0; Mt < 4; ++Mt)
                #pragma unroll
                for (int r = 0; r < 4; ++r) { float e = __expf(sacc[Mt][r] - mx); ee[Mt][r] = e; sum += e; }
            sum += __shfl_xor(sum, 16, 64);
            sum += __shfl_xor(sum, 32, 64);
            float inv = 1.0f / sum;
            #pragma unroll
            for (int Mt = 0; Mt < 4; ++Mt)
                #pragma unroll
                for (int r = 0; r < 4; ++r) {
                    int c = h * 64 + Mt * 16 + kg * 4 + r;
                    *(unsigned short*)(bufA + swzB(Nt * 16 + lr, c * 2)) = f2bf(ee[Mt][r] * inv);
                }
        }
    }
    __syncthreads();

    // ---- out = LN([abuf|pebf] @ Wcat + bo + bp), pipelined K=12 steps ----
    const int n0 = w * 96;
    const unsigned short* wptr[6];
    #pragma unroll
    for (int nt = 0; nt < 6; ++nt)
        wptr[nt] = Wcat + (size_t)(n0 + nt * 16 + lr) * KW + kg * 8;

    #pragma unroll
    for (int half = 0; half < 2; ++half) {
        f32x4 acc[6][2];
        #pragma unroll
        for (int nt = 0; nt < 6; ++nt) {
            int col = n0 + nt * 16 + lr;
            float bias = bo[col] + bp[col];
            acc[nt][0] = (f32x4){bias, bias, bias, bias};
            acc[nt][1] = (f32x4){bias, bias, bias, bias};
        }
        bf16x8 b0[6], b1[6];
        #pragma unroll
        for (int nt = 0; nt < 6; ++nt) b0[nt] = *(const bf16x8*)(wptr[nt]);
        #pragma unroll
        for (int kkc = 0; kkc < 3; ++kkc) {
            #pragma unroll
            for (int kk = 0; kk < 4; ++kk) {
                const int ks = kkc * 4 + kk;
                // A-frags for this k-step (LDS, cheap)
                bf16x8 aw0, aw1;
                if (kkc < 2) {
                    aw0 = *(const bf16x8*)(bufA + swzB((half * 2 + 0) * 16 + lr, (kkc * 128 + kk * 32 + kg * 8) * 2));
                    aw1 = *(const bf16x8*)(bufA + swzB((half * 2 + 1) * 16 + lr, (kkc * 128 + kk * 32 + kg * 8) * 2));
                } else {
                    aw0 = *(const bf16x8*)(pebf + swzP((half * 2 + 0) * 16 + lr, (kk * 32 + kg * 8) * 2));
                    aw1 = *(const bf16x8*)(pebf + swzP((half * 2 + 1) * 16 + lr, (kk * 32 + kg * 8) * 2));
                }
                // prefetch next k-step's B frags into the other buffer
                if (ks + 1 < 12) {
                    if ((ks & 1) == 0) {
                        #pragma unroll
                        for (int nt = 0; nt < 6; ++nt)
                            b1[nt] = *(const bf16x8*)(wptr[nt] + (ks + 1) * 32);
                    } else {
                        #pragma unroll
                        for (int nt = 0; nt < 6; ++nt)
                            b0[nt] = *(const bf16x8*)(wptr[nt] + (ks + 1) * 32);
                    }
                }
                // MFMA with current buffer
                if ((ks & 1) == 0) {
                    #pragma unroll
                    for (int nt = 0; nt < 6; ++nt) {
                        acc[nt][0] = __builtin_amdgcn_mfma_f32_16x16x32_bf16(aw0, b0[nt], acc[nt][0], 0, 0, 0);
                        acc[nt][1] = __builtin_amdgcn_mfma_f32_16x16x32_bf16(aw1, b0[nt], acc[nt][1], 0, 0, 0);
                    }
                } else {
                    #pragma unroll
                    for (int nt = 0; nt < 6; ++nt) {
                        acc[nt][0] = __builtin_amdgcn_mfma_f32_16x16x32_bf16(aw0, b1[nt], acc[nt][0], 0, 0, 0);
                        acc[nt][1] = __builtin_amdgcn_mfma_f32_16x16x32_bf16(aw1, b1[nt], acc[nt][1], 0, 0, 0);
                    }
                }
            }
        }
        // LN stats: per-lane over nt, reduce over 16 lr lanes, cross-wave LDS
        #pragma unroll
        for (int Mtl = 0; Mtl < 2; ++Mtl)
            #pragma unroll
            for (int r = 0; r < 4; ++r) {
                float s = 0.f, q = 0.f;
                #pragma unroll
                for (int nt = 0; nt < 6; ++nt) { float v = acc[nt][Mtl][r]; s += v; q += v * v; }
                #pragma unroll
                for (int off = 8; off; off >>= 1) {
                    s += __shfl_xor(s, off, 64);
                    q += __shfl_xor(q, off, 64);
                }
                if (lr == 0) {
                    int tok = (half * 2 + Mtl) * 16 + kg * 4 + r;
                    redS [w][tok] = s;
                    redS2[w][tok] = q;
                }
            }
        __syncthreads();
        #pragma unroll
        for (int Mtl = 0; Mtl < 2; ++Mtl) {
            float mA[4], riA[4];
            #pragma unroll
            for (int r = 0; r < 4; ++r) {
                int tok = (half * 2 + Mtl) * 16 + kg * 4 + r;
                float ts = 0.f, tq = 0.f;
                #pragma unroll
                for (int ww = 0; ww < 8; ++ww) { ts += redS[ww][tok]; tq += redS2[ww][tok]; }
                float mm  = ts / DM;
                float var = tq / DM - mm * mm;
                mA[r]  = mm;
                riA[r] = 1.0f / sqrtf(var + EPSF);
            }
            #pragma unroll
            for (int nt = 0; nt < 6; ++nt) {
                int col = n0 + nt * 16 + lr;
                float g = on_g[col], bb = on_b[col];
                #pragma unroll
                for (int r = 0; r < 4; ++r) {
                    int tok = (half * 2 + Mtl) * 16 + kg * 4 + r;
                    int t = tok & 15, rr = tok >> 4;
                    int gr = nb * RPB + rr;
                    if (t < NTOK && gr < Nrows)
                        out[((size_t)gr * NTOK + t) * DM + col] =
                            (acc[nt][Mtl][r] - mA[r]) * riA[r] * g + bb;
                }
            }
        }
    }
}

extern "C" void kernel_launch(void* const* d_in, const int* in_sizes, int n_in,
                              void* d_out, int out_size, void* d_ws, size_t ws_size,
                              hipStream_t stream) {
    const float* state    = (const float*)d_in[0];
    const float* w_scalar = (const float*)d_in[1];
    const float* b_scalar = (const float*)d_in[2];
    const float* w_patch  = (const float*)d_in[3];
    const float* b_patch  = (const float*)d_in[4];
    const float* feat_emb = (const float*)d_in[5];
    const float* pn_g     = (const float*)d_in[6];
    const float* pn_b     = (const float*)d_in[7];
    const float* wq       = (const float*)d_in[8];
    const float* bq       = (const float*)d_in[9];
    const float* wk       = (const float*)d_in[10];
    const float* bk       = (const float*)d_in[11];
    const float* wv       = (const float*)d_in[12];
    const float* bv       = (const float*)d_in[13];
    const float* wp       = (const float*)d_in[14];
    const float* bp       = (const float*)d_in[15];
    const float* wo       = (const float*)d_in[16];
    const float* bo       = (const float*)d_in[17];
    const float* on_g     = (const float*)d_in[18];
    const float* on_b     = (const float*)d_in[19];
    const float* protos   = (const float*)d_in[20];
    float* out = (float*)d_out;

    float*          Kraw = (float*)d_ws;                    // 256*192 f32
    float*          Vf   = Kraw + 256 * HD;                 // 64*768  f32
    float*          kqbp = Vf + NP * DM;                    // 256     f32
    unsigned short* KWb  = (unsigned short*)(kqbp + 256);   // [256][128] bf16
    unsigned short* Wcat = KWb + 256 * DP;                  // [768][384] bf16

    int N = in_sizes[0] / 36;
    int nblk = (N + RPB - 1) / RPB;

    hipLaunchKernelGGL(kv_kernel, dim3(NP), dim3(DM), 0, stream,
                       protos, wk, bk, wv, bv, Kraw, Vf);
    hipLaunchKernelGGL(fold_kernel, dim3(640), dim3(256), 0, stream,
                       Kraw, Vf, wq, bq, wo, wp, KWb, kqbp, Wcat);
    hipLaunchKernelGGL(row_kernel, dim3(nblk), dim3(TPB), 0, stream,
                       state, w_scalar, b_scalar, w_patch, b_patch, feat_emb,
                       pn_g, pn_b, KWb, kqbp, Wcat, bp, bo, on_g, on_b,
                       out, N);
}

// Round 11
// 297.053 us; speedup vs baseline: 22.5209x; 1.0441x over previous
//
#include <hip/hip_runtime.h>

#define NTOK 15
#define DP   128
#define DM   768
#define NH   4
#define HD   192
#define NP   64
#define EPSF 1e-5f
#define KW2  384    // [attn(256) | pe(128)]

typedef __attribute__((ext_vector_type(8))) short bf16x8;   // 8 bf16 = 4 VGPR
typedef __attribute__((ext_vector_type(4))) float f32x4;
typedef __attribute__((ext_vector_type(4))) unsigned short us4;

__device__ __forceinline__ unsigned short f2bf(float x) {
    unsigned u = __float_as_uint(x);
    u = (u + 0x7FFF + ((u >> 16) & 1)) >> 16;   // RNE
    return (unsigned short)u;
}
// swizzled LDS byte addresses (row strides 256B / 512B)
__device__ __forceinline__ int swzP(int row, int b) { return row * 256 + (b ^ ((row & 7) << 4)); }
__device__ __forceinline__ int swzB(int row, int b) { return row * 512 + (b ^ ((row & 7) << 4)); }

// ---------------------------------------------------------------------------
// P1: Kraw[hp][192] f32 and Vf[p][768] f32 from protos. 256 blocks x 192 thr.
// ---------------------------------------------------------------------------
__global__ __launch_bounds__(192) void kv_kernel(
    const float* __restrict__ protos,
    const float* __restrict__ wk, const float* __restrict__ bk,
    const float* __restrict__ wv, const float* __restrict__ bv,
    float* __restrict__ Kraw, float* __restrict__ Vf)
{
    int r  = blockIdx.x >> 2;          // proto 0..63
    int jc = blockIdx.x & 3;           // col-chunk
    int j  = jc * 192 + threadIdx.x;   // col 0..767
    __shared__ float prow[DM];
    for (int i = threadIdx.x; i < DM; i += 192) prow[i] = protos[r * DM + i];
    __syncthreads();
    float aK = bk[j], aV = bv[j];
    for (int d = 0; d < DM; ++d) {
        float p = prow[d];
        aK += p * wk[d * DM + j];
        aV += p * wv[d * DM + j];
    }
    int h = j / HD, jj = j - h * HD;
    Kraw[(h * NP + r) * HD + jj] = aK;
    Vf[r * DM + j] = aV;
}

// ---------------------------------------------------------------------------
// P2: fold K/V into weights + build Wcat (unchanged from r10, verified).
// ---------------------------------------------------------------------------
__global__ __launch_bounds__(256) void fold_kernel(
    const float* __restrict__ Kraw, const float* __restrict__ Vf,
    const float* __restrict__ wq, const float* __restrict__ bq,
    const float* __restrict__ wo, const float* __restrict__ wp,
    unsigned short* __restrict__ KWb, float* __restrict__ kqb,
    unsigned short* __restrict__ Wcat)
{
    int b = blockIdx.x, tid = threadIdx.x;
    if (b >= 256) {
        int idx = (b - 256) * 256 + tid;
        int j = idx >> 7, d = idx & 127;
        Wcat[(size_t)j * KW2 + 256 + d] = f2bf(wp[d * DM + j]);
        return;
    }
    int hp = b, h = hp >> 6, p = hp & 63;
    __shared__ float Kl[HD], Vl[HD];
    if (tid < HD) {
        Kl[tid] = Kraw[hp * HD + tid];
        Vl[tid] = Vf[p * DM + h * HD + tid];
    }
    __syncthreads();
    const float scale = 0.07216878364870323f;   // 1/sqrt(192)
    if (tid < DP) {
        float a = 0.f;
        for (int l = 0; l < HD; ++l) a += wq[tid * DM + h * HD + l] * Kl[l];
        KWb[hp * DP + tid] = f2bf(scale * a);
    } else if (tid == DP) {
        float a = 0.f;
        for (int l = 0; l < HD; ++l) a += bq[h * HD + l] * Kl[l];
        kqb[hp] = scale * a;
    }
    for (int jj = 0; jj < 3; ++jj) {
        int j = jj * 256 + tid;
        float a = 0.f;
        for (int l = 0; l < HD; ++l) a += wo[(h * HD + l) * DM + j] * Vl[l];
        Wcat[(size_t)j * KW2 + hp] = f2bf(a);
    }
}

// ---------------------------------------------------------------------------
// Phase A: 2 state-rows (32 token-rows) per block, 256 thr / 4 waves.
// pe build -> LN -> scores (MFMA) -> softmax -> [attn|pe] bf16 to abufG.
// LDS ~25KB -> high occupancy; grid ceil(N/2).
// ---------------------------------------------------------------------------
__global__ __launch_bounds__(256, 4) void phaseA_kernel(
    const float* __restrict__ state,
    const float* __restrict__ w_scalar, const float* __restrict__ b_scalar,
    const float* __restrict__ w_patch,  const float* __restrict__ b_patch,
    const float* __restrict__ feat_emb,
    const float* __restrict__ pn_g, const float* __restrict__ pn_b,
    const unsigned short* __restrict__ KWb, const float* __restrict__ kqb,
    unsigned short* __restrict__ abufG, int Nrows)
{
    int tid = threadIdx.x;
    int w = tid >> 6, lane = tid & 63;
    int kg = lane >> 4, lr = lane & 15;
    int nb = blockIdx.x;
    size_t rowbase = (size_t)nb * 32;

    __shared__ float peF[32 * DP];          // 16KB
    __shared__ __align__(16) char pebf[32 * 256];  // 8KB swizzled bf16
    __shared__ float srow[72];

    if (tid < 72) {
        int rr = tid / 36;
        int gr = nb * 2 + rr;
        srow[tid] = (gr < Nrows) ? state[(size_t)gr * 36 + (tid - rr * 36)] : 0.f;
    }
    __syncthreads();

    // ---- build pe f32 (32 rows x 128) ------------------------------------
    #pragma unroll
    for (int it = 0; it < 16; ++it) {
        int idx = it * 256 + tid;
        int row = idx >> 7, d = idx & 127;
        int t = row & 15;
        const float* sr = &srow[(row >> 4) * 36];
        float val;
        if (t == 15) {
            val = 0.f;
        } else if (t == 0) {
            val = sr[5]  * w_scalar[0 * DP + d] + b_scalar[0 * DP + d] + feat_emb[0 * DP + d];
        } else if (t == 1) {
            val = sr[11] * w_scalar[1 * DP + d] + b_scalar[1 * DP + d] + feat_emb[1 * DP + d];
        } else if (t == 14) {
            val = sr[35] * w_scalar[2 * DP + d] + b_scalar[2 * DP + d] + feat_emb[5 * DP + d];
        } else {
            int f = (t - 2) / 4;
            int k = (t - 2) % 4;
            const float* pr = &sr[(2 + f) * 6];
            float acc = b_patch[f * DP + d] + feat_emb[(2 + f) * DP + d];
            for (int p = 0; p < 3; ++p) acc += pr[k + p] * w_patch[(f * 3 + p) * DP + d];
            val = acc;
        }
        peF[row * DP + d] = val;
    }
    __syncthreads();

    // ---- LayerNorm -> pebf bf16 swizzled (8 lanes per token-row) ---------
    {
        int g = tid >> 3, ln = tid & 7;     // g = 0..31
        int t = g & 15;
        int gr = nb * 2 + (g >> 4);
        if (t == 15 || gr >= Nrows) {
            for (int d = ln; d < DP; d += 8)
                *(unsigned short*)(pebf + swzP(g, d * 2)) = 0;
        } else {
            float s = 0.f, s2 = 0.f;
            for (int d = ln; d < DP; d += 8) { float x = peF[g * DP + d]; s += x; s2 += x * x; }
            for (int off = 4; off; off >>= 1) {
                s  += __shfl_xor(s,  off, 64);
                s2 += __shfl_xor(s2, off, 64);
            }
            float m   = s / DP;
            float var = s2 / DP - m * m;
            float rin = 1.0f / sqrtf(var + EPSF);
            for (int d = ln; d < DP; d += 8) {
                float x = (peF[g * DP + d] - m) * rin * pn_g[d] + pn_b[d];
                *(unsigned short*)(pebf + swzP(g, d * 2)) = f2bf(x);
            }
        }
    }
    __syncthreads();

    // ---- scores = KW @ pe^T + kqb; softmax; attn -> abufG ----------------
    {
        const int h = w;                       // wave == head
        const unsigned short* kwh = KWb + (size_t)h * NP * DP;
        bf16x8 ka[4][4];
        float4 kqv[4];
        #pragma unroll
        for (int Mt = 0; Mt < 4; ++Mt) {
            #pragma unroll
            for (int kk = 0; kk < 4; ++kk)
                ka[Mt][kk] = *(const bf16x8*)(kwh + (Mt * 16 + lr) * DP + kk * 32 + kg * 8);
            kqv[Mt] = *(const float4*)(kqb + h * 64 + Mt * 16 + kg * 4);
        }
        #pragma unroll
        for (int Ntl = 0; Ntl < 2; ++Ntl) {
            bf16x8 qb[4];
            #pragma unroll
            for (int kk = 0; kk < 4; ++kk)
                qb[kk] = *(const bf16x8*)(pebf + swzP(Ntl * 16 + lr, (kk * 32 + kg * 8) * 2));
            f32x4 sacc[4];
            #pragma unroll
            for (int Mt = 0; Mt < 4; ++Mt) sacc[Mt] = (f32x4){0.f, 0.f, 0.f, 0.f};
            #pragma unroll
            for (int kk = 0; kk < 4; ++kk)
                #pragma unroll
                for (int Mt = 0; Mt < 4; ++Mt)
                    sacc[Mt] = __builtin_amdgcn_mfma_f32_16x16x32_bf16(ka[Mt][kk], qb[kk], sacc[Mt], 0, 0, 0);
            #pragma unroll
            for (int Mt = 0; Mt < 4; ++Mt) {
                sacc[Mt][0] += kqv[Mt].x; sacc[Mt][1] += kqv[Mt].y;
                sacc[Mt][2] += kqv[Mt].z; sacc[Mt][3] += kqv[Mt].w;
            }
            float mx = -3.4e38f;
            #pragma unroll
            for (int Mt = 0; Mt < 4; ++Mt)
                #pragma unroll
                for (int r = 0; r < 4; ++r) mx = fmaxf(mx, sacc[Mt][r]);
            mx = fmaxf(mx, __shfl_xor(mx, 16, 64));
            mx = fmaxf(mx, __shfl_xor(mx, 32, 64));
            float sum = 0.f;
            f32x4 ee[4];
            #pragma unroll
            for (int Mt = 0; Mt < 4; ++Mt)
                #pragma unroll
                for (int r = 0; r < 4; ++r) { float e = __expf(sacc[Mt][r] - mx); ee[Mt][r] = e; sum += e; }
            sum += __shfl_xor(sum, 16, 64);
            sum += __shfl_xor(sum, 32, 64);
            float inv = 1.0f / sum;
            unsigned short* dst = abufG + (rowbase + Ntl * 16 + lr) * KW2 + h * 64 + kg * 4;
            #pragma unroll
            for (int Mt = 0; Mt < 4; ++Mt) {
                us4 v = { f2bf(ee[Mt][0] * inv), f2bf(ee[Mt][1] * inv),
                          f2bf(ee[Mt][2] * inv), f2bf(ee[Mt][3] * inv) };
                *(us4*)(dst + Mt * 16) = v;
            }
        }
    }

    // ---- pe bf16 -> abufG cols 256..383 (coalesced 16B) ------------------
    #pragma unroll
    for (int c = 0; c < 2; ++c) {
        int idx = c * 256 + tid;            // 0..511
        int row = idx >> 4, chunk = idx & 15;
        bf16x8 v = *(const bf16x8*)(pebf + swzP(row, chunk * 16));
        *(bf16x8*)(abufG + (rowbase + row) * KW2 + 256 + chunk * 8) = v;
    }
}

// ---------------------------------------------------------------------------
// Phase B: pure streaming GEMM out = LN(A[64x384] @ Wcat^T + bias).
// 512 thr / 8 waves x 96 cols; NO barriers in K-loop; LDS-staged C-write.
// ---------------------------------------------------------------------------
__global__ __launch_bounds__(512, 2) void phaseB_kernel(
    const unsigned short* __restrict__ abufG,
    const unsigned short* __restrict__ Wcat,
    const float* __restrict__ bp, const float* __restrict__ bo,
    const float* __restrict__ on_g, const float* __restrict__ on_b,
    float* __restrict__ out, int Nrows)
{
    int tid = threadIdx.x;
    int w = tid >> 6, lane = tid & 63;
    int kg = lane >> 4, lr = lane & 15;
    int nb = blockIdx.x;
    const int n0 = w * 96;

    __shared__ __align__(16) float stage[16 * 772];      // 49.4KB
    __shared__ float redS[8][64], redS2[8][64];

    const unsigned short* aptr = abufG + (size_t)nb * 64 * KW2;

    float gcol[6], bcol[6];
    f32x4 acc[6][4];
    #pragma unroll
    for (int nt = 0; nt < 6; ++nt) {
        int col = n0 + nt * 16 + lr;
        gcol[nt] = on_g[col]; bcol[nt] = on_b[col];
        float bias = bo[col] + bp[col];
        #pragma unroll
        for (int Mt = 0; Mt < 4; ++Mt) acc[nt][Mt] = (f32x4){bias, bias, bias, bias};
    }

    // ---- K-loop: 12 steps, fully unrolled, no barriers -------------------
    #pragma unroll
    for (int ks = 0; ks < 12; ++ks) {
        bf16x8 aw[4];
        #pragma unroll
        for (int Mt = 0; Mt < 4; ++Mt)
            aw[Mt] = *(const bf16x8*)(aptr + (Mt * 16 + lr) * KW2 + ks * 32 + kg * 8);
        #pragma unroll
        for (int nt = 0; nt < 6; ++nt) {
            bf16x8 b = *(const bf16x8*)(Wcat + (size_t)(n0 + nt * 16 + lr) * KW2 + ks * 32 + kg * 8);
            #pragma unroll
            for (int Mt = 0; Mt < 4; ++Mt)
                acc[nt][Mt] = __builtin_amdgcn_mfma_f32_16x16x32_bf16(aw[Mt], b, acc[nt][Mt], 0, 0, 0);
        }
    }

    // ---- LN stats --------------------------------------------------------
    #pragma unroll
    for (int Mt = 0; Mt < 4; ++Mt)
        #pragma unroll
        for (int r = 0; r < 4; ++r) {
            float s = 0.f, q = 0.f;
            #pragma unroll
            for (int nt = 0; nt < 6; ++nt) { float v = acc[nt][Mt][r]; s += v; q += v * v; }
            #pragma unroll
            for (int off = 8; off; off >>= 1) {
                s += __shfl_xor(s, off, 64);
                q += __shfl_xor(q, off, 64);
            }
            if (lr == 0) {
                int tok = Mt * 16 + kg * 4 + r;
                redS [w][tok] = s;
                redS2[w][tok] = q;
            }
        }
    __syncthreads();
    float mA[4][4], riA[4][4];
    #pragma unroll
    for (int Mt = 0; Mt < 4; ++Mt)
        #pragma unroll
        for (int r = 0; r < 4; ++r) {
            int tok = Mt * 16 + kg * 4 + r;
            float ts = 0.f, tq = 0.f;
            #pragma unroll
            for (int ww = 0; ww < 8; ++ww) { ts += redS[ww][tok]; tq += redS2[ww][tok]; }
            float mm  = ts / DM;
            float var = tq / DM - mm * mm;
            mA[Mt][r]  = mm;
            riA[Mt][r] = 1.0f / sqrtf(var + EPSF);
        }

    // ---- staged coalesced write: one 16-row tile (= one source row) at a time
    #pragma unroll
    for (int Mt = 0; Mt < 4; ++Mt) {
        __syncthreads();
        #pragma unroll
        for (int nt = 0; nt < 6; ++nt)
            #pragma unroll
            for (int r = 0; r < 4; ++r)
                stage[(kg * 4 + r) * 772 + n0 + nt * 16 + lr] =
                    (acc[nt][Mt][r] - mA[Mt][r]) * riA[Mt][r] * gcol[nt] + bcol[nt];
        __syncthreads();
        int gr = nb * 4 + Mt;
        if (gr < Nrows) {
            #pragma unroll
            for (int v = 0; v < 6; ++v) {
                int f = v * 512 + tid;          // 0..3071
                int row = f / 192, c4 = f - row * 192;
                if (row < NTOK)
                    *(float4*)(out + ((size_t)gr * NTOK + row) * DM + c4 * 4) =
                        *(const float4*)(&stage[row * 772 + c4 * 4]);
            }
        }
    }
}

// ---------------------------------------------------------------------------
// Fallback: round-10 fused kernel (used only if ws_size too small).
// ---------------------------------------------------------------------------
__global__ __launch_bounds__(512, 4) void row_fused_kernel(
    const float* __restrict__ state,
    const float* __restrict__ w_scalar, const float* __restrict__ b_scalar,
    const float* __restrict__ w_patch,  const float* __restrict__ b_patch,
    const float* __restrict__ feat_emb,
    const float* __restrict__ pn_g, const float* __restrict__ pn_b,
    const unsigned short* __restrict__ KWb, const float* __restrict__ kqb,
    const unsigned short* __restrict__ Wcat,
    const float* __restrict__ bp, const float* __restrict__ bo,
    const float* __restrict__ on_g, const float* __restrict__ on_b,
    float* __restrict__ out, int Nrows)
{
    int tid = threadIdx.x;
    int w = tid >> 6, lane = tid & 63;
    int kg = lane >> 4, lr = lane & 15;
    int nb = blockIdx.x;

    __shared__ __align__(16) char bufA[64 * 512];
    __shared__ __align__(16) char pebf[64 * 256];
    __shared__ float srow[4 * 36];
    __shared__ float redS[8][64], redS2[8][64];

    float* peF = (float*)bufA;

    if (tid < 4 * 36) {
        int rr = tid / 36;
        int gr = nb * 4 + rr;
        srow[tid] = (gr < Nrows) ? state[(size_t)gr * 36 + (tid - rr * 36)] : 0.f;
    }
    __syncthreads();

    for (int idx = tid; idx < 4 * NTOK * DP; idx += 512) {
        int rr  = idx / (NTOK * DP);
        int rem = idx - rr * (NTOK * DP);
        int t = rem >> 7, d = rem & 127;
        const float* sr = &srow[rr * 36];
        float val;
        if (t == 0) {
            val = sr[5]  * w_scalar[0 * DP + d] + b_scalar[0 * DP + d] + feat_emb[0 * DP + d];
        } else if (t == 1) {
            val = sr[11] * w_scalar[1 * DP + d] + b_scalar[1 * DP + d] + feat_emb[1 * DP + d];
        } else if (t == 14) {
            val = sr[35] * w_scalar[2 * DP + d] + b_scalar[2 * DP + d] + feat_emb[5 * DP + d];
        } else {
            int f = (t - 2) / 4;
            int k = (t - 2) % 4;
            const float* pr = &sr[(2 + f) * 6];
            float acc = b_patch[f * DP + d] + feat_emb[(2 + f) * DP + d];
            for (int p = 0; p < 3; ++p) acc += pr[k + p] * w_patch[(f * 3 + p) * DP + d];
            val = acc;
        }
        peF[(rr * 16 + t) * DP + d] = val;
    }
    __syncthreads();

    const int h = w >> 1;
    bf16x8 ka[4][4];
    float4 kqv[4];
    {
        const unsigned short* kwh = KWb + (size_t)h * NP * DP;
        #pragma unroll
        for (int Mt = 0; Mt < 4; ++Mt) {
            #pragma unroll
            for (int kk = 0; kk < 4; ++kk)
                ka[Mt][kk] = *(const bf16x8*)(kwh + (Mt * 16 + lr) * DP + kk * 32 + kg * 8);
            kqv[Mt] = *(const float4*)(kqb + h * 64 + Mt * 16 + kg * 4);
        }
    }

    {
        int g = tid >> 3, ln = tid & 7;
        int t = g & 15;
        int gr = nb * 4 + (g >> 4);
        if (t == 15 || gr >= Nrows) {
            for (int d = ln; d < DP; d += 8)
                *(unsigned short*)(pebf + swzP(g, d * 2)) = 0;
        } else {
            float s = 0.f, s2 = 0.f;
            for (int d = ln; d < DP; d += 8) { float x = peF[g * DP + d]; s += x; s2 += x * x; }
            for (int off = 4; off; off >>= 1) {
                s  += __shfl_xor(s,  off, 64);
                s2 += __shfl_xor(s2, off, 64);
            }
            float m   = s / DP;
            float var = s2 / DP - m * m;
            float rin = 1.0f / sqrtf(var + EPSF);
            for (int d = ln; d < DP; d += 8) {
                float x = (peF[g * DP + d] - m) * rin * pn_g[d] + pn_b[d];
                *(unsigned short*)(pebf + swzP(g, d * 2)) = f2bf(x);
            }
        }
    }
    __syncthreads();

    {
        int Nt0 = (w & 1) * 2;
        #pragma unroll
        for (int Ntl = 0; Ntl < 2; ++Ntl) {
            int Nt = Nt0 + Ntl;
            bf16x8 qb[4];
            #pragma unroll
            for (int kk = 0; kk < 4; ++kk)
                qb[kk] = *(const bf16x8*)(pebf + swzP(Nt * 16 + lr, (kk * 32 + kg * 8) * 2));
            f32x4 sacc[4];
            #pragma unroll
            for (int Mt = 0; Mt < 4; ++Mt) sacc[Mt] = (f32x4){0.f, 0.f, 0.f, 0.f};
            #pragma unroll
            for (int kk = 0; kk < 4; ++kk)
                #pragma unroll
                for (int Mt = 0; Mt < 4; ++Mt)
                    sacc[Mt] = __builtin_amdgcn_mfma_f32_16x16x32_bf16(ka[Mt][kk], qb[kk], sacc[Mt], 0, 0, 0);
            #pragma unroll
            for (int Mt = 0; Mt < 4; ++Mt) {
                sacc[Mt][0] += kqv[Mt].x; sacc[Mt][1] += kqv[Mt].y;
                sacc[Mt][2] += kqv[Mt].z; sacc[Mt][3] += kqv[Mt].w;
            }
            float mx = -3.4e38f;
            #pragma unroll
            for (int Mt = 0; Mt < 4; ++Mt)
                #pragma unroll
                for (int r = 0; r < 4; ++r) mx = fmaxf(mx, sacc[Mt][r]);
            mx = fmaxf(mx, __shfl_xor(mx, 16, 64));
            mx = fmaxf(mx, __shfl_xor(mx, 32, 64));
            float sum = 0.f;
            f32x4 ee[4];
            #pragma unroll
            for (int Mt = 0; Mt < 4; ++Mt)
                #pragma unroll
                for (int r = 0; r < 4; ++r) { float e = __expf(sacc[Mt][r] - mx); ee[Mt][r] = e; sum += e; }
            sum += __shfl_xor(sum, 16, 64);
            sum += __shfl_xor(sum, 32, 64);
            float inv = 1.0f / sum;
            #pragma unroll
            for (int Mt = 0; Mt < 4; ++Mt)
                #pragma unroll
                for (int r = 0; r < 4; ++r) {
                    int c = h * 64 + Mt * 16 + kg * 4 + r;
                    *(unsigned short*)(bufA + swzB(Nt * 16 + lr, c * 2)) = f2bf(ee[Mt][r] * inv);
                }
        }
    }
    __syncthreads();

    const int n0 = w * 96;
    #pragma unroll
    for (int half = 0; half < 2; ++half) {
        f32x4 acc[6][2];
        #pragma unroll
        for (int nt = 0; nt < 6; ++nt) {
            int col = n0 + nt * 16 + lr;
            float bias = bo[col] + bp[col];
            acc[nt][0] = (f32x4){bias, bias, bias, bias};
            acc[nt][1] = (f32x4){bias, bias, bias, bias};
        }
        #pragma unroll
        for (int kkc = 0; kkc < 3; ++kkc) {
            #pragma unroll
            for (int kk = 0; kk < 4; ++kk) {
                bf16x8 aw0, aw1;
                if (kkc < 2) {
                    aw0 = *(const bf16x8*)(bufA + swzB((half * 2 + 0) * 16 + lr, (kkc * 128 + kk * 32 + kg * 8) * 2));
                    aw1 = *(const bf16x8*)(bufA + swzB((half * 2 + 1) * 16 + lr, (kkc * 128 + kk * 32 + kg * 8) * 2));
                } else {
                    aw0 = *(const bf16x8*)(pebf + swzP((half * 2 + 0) * 16 + lr, (kk * 32 + kg * 8) * 2));
                    aw1 = *(const bf16x8*)(pebf + swzP((half * 2 + 1) * 16 + lr, (kk * 32 + kg * 8) * 2));
                }
                int ks = kkc * 4 + kk;
                #pragma unroll
                for (int nt = 0; nt < 6; ++nt) {
                    bf16x8 b = *(const bf16x8*)(Wcat + (size_t)(n0 + nt * 16 + lr) * KW2 + ks * 32 + kg * 8);
                    acc[nt][0] = __builtin_amdgcn_mfma_f32_16x16x32_bf16(aw0, b, acc[nt][0], 0, 0, 0);
                    acc[nt][1] = __builtin_amdgcn_mfma_f32_16x16x32_bf16(aw1, b, acc[nt][1], 0, 0, 0);
                }
            }
        }
        #pragma unroll
        for (int Mtl = 0; Mtl < 2; ++Mtl)
            #pragma unroll
            for (int r = 0; r < 4; ++r) {
                float s = 0.f, q = 0.f;
                #pragma unroll
                for (int nt = 0; nt < 6; ++nt) { float v = acc[nt][Mtl][r]; s += v; q += v * v; }
                #pragma unroll
                for (int off = 8; off; off >>= 1) {
                    s += __shfl_xor(s, off, 64);
                    q += __shfl_xor(q, off, 64);
                }
                if (lr == 0) {
                    int tok = (half * 2 + Mtl) * 16 + kg * 4 + r;
                    redS [w][tok] = s;
                    redS2[w][tok] = q;
                }
            }
        __syncthreads();
        #pragma unroll
        for (int Mtl = 0; Mtl < 2; ++Mtl) {
            float mA[4], riA[4];
            #pragma unroll
            for (int r = 0; r < 4; ++r) {
                int tok = (half * 2 + Mtl) * 16 + kg * 4 + r;
                float ts = 0.f, tq = 0.f;
                #pragma unroll
                for (int ww = 0; ww < 8; ++ww) { ts += redS[ww][tok]; tq += redS2[ww][tok]; }
                float mm  = ts / DM;
                float var = tq / DM - mm * mm;
                mA[r]  = mm;
                riA[r] = 1.0f / sqrtf(var + EPSF);
            }
            #pragma unroll
            for (int nt = 0; nt < 6; ++nt) {
                int col = n0 + nt * 16 + lr;
                float g = on_g[col], bb = on_b[col];
                #pragma unroll
                for (int r = 0; r < 4; ++r) {
                    int tok = (half * 2 + Mtl) * 16 + kg * 4 + r;
                    int t = tok & 15, rr = tok >> 4;
                    int gr = nb * 4 + rr;
                    if (t < NTOK && gr < Nrows)
                        out[((size_t)gr * NTOK + t) * DM + col] =
                            (acc[nt][Mtl][r] - mA[r]) * riA[r] * g + bb;
                }
            }
        }
    }
}

extern "C" void kernel_launch(void* const* d_in, const int* in_sizes, int n_in,
                              void* d_out, int out_size, void* d_ws, size_t ws_size,
                              hipStream_t stream) {
    const float* state    = (const float*)d_in[0];
    const float* w_scalar = (const float*)d_in[1];
    const float* b_scalar = (const float*)d_in[2];
    const float* w_patch  = (const float*)d_in[3];
    const float* b_patch  = (const float*)d_in[4];
    const float* feat_emb = (const float*)d_in[5];
    const float* pn_g     = (const float*)d_in[6];
    const float* pn_b     = (const float*)d_in[7];
    const float* wq       = (const float*)d_in[8];
    const float* bq       = (const float*)d_in[9];
    const float* wk       = (const float*)d_in[10];
    const float* bk       = (const float*)d_in[11];
    const float* wv       = (const float*)d_in[12];
    const float* bv       = (const float*)d_in[13];
    const float* wp       = (const float*)d_in[14];
    const float* bp       = (const float*)d_in[15];
    const float* wo       = (const float*)d_in[16];
    const float* bo       = (const float*)d_in[17];
    const float* on_g     = (const float*)d_in[18];
    const float* on_b     = (const float*)d_in[19];
    const float* protos   = (const float*)d_in[20];
    float* out = (float*)d_out;

    float*          Kraw = (float*)d_ws;                    // 49152 f32
    float*          Vf   = Kraw + 256 * HD;                 // 49152 f32
    float*          kqbp = Vf + NP * DM;                    // 256   f32
    unsigned short* KWb  = (unsigned short*)(kqbp + 256);   // 32768 us
    unsigned short* Wcat = KWb + 256 * DP;                  // 294912 us
    unsigned short* abufG = Wcat + (size_t)DM * KW2;

    int N = in_sizes[0] / 36;
    int nblkA = (N + 1) / 2;
    int nblkB = (N + 3) / 4;
    size_t tokrows = (size_t)nblkB * 64;
    size_t need = 1049600ull + tokrows * KW2 * 2ull;        // base + abuf bytes

    hipLaunchKernelGGL(kv_kernel, dim3(256), dim3(192), 0, stream,
                       protos, wk, bk, wv, bv, Kraw, Vf);
    hipLaunchKernelGGL(fold_kernel, dim3(640), dim3(256), 0, stream,
                       Kraw, Vf, wq, bq, wo, wp, KWb, kqbp, Wcat);

    if (ws_size >= need) {
        hipLaunchKernelGGL(phaseA_kernel, dim3(nblkA), dim3(256), 0, stream,
                           state, w_scalar, b_scalar, w_patch, b_patch, feat_emb,
                           pn_g, pn_b, KWb, kqbp, abufG, N);
        hipLaunchKernelGGL(phaseB_kernel, dim3(nblkB), dim3(512), 0, stream,
                           abufG, Wcat, bp, bo, on_g, on_b, out, N);
    } else {
        hipLaunchKernelGGL(row_fused_kernel, dim3(nblkB), dim3(512), 0, stream,
                           state, w_scalar, b_scalar, w_patch, b_patch, feat_emb,
                           pn_g, pn_b, KWb, kqbp, Wcat, bp, bo, on_g, on_b,
                           out, N);
    }
}